// Round 1
// baseline (817.667 us; speedup 1.0000x reference)
//
#include <hip/hip_runtime.h>
#include <hip/hip_bf16.h>

#define B_    16
#define O_    80
#define R_    512
#define INCH  4096
#define NCLS  151
#define EMB_  768
#define HID_  512
#define POOL_ 2048
#define GEO_  128

typedef unsigned short u16;
typedef __attribute__((ext_vector_type(4))) float  f32x4;
typedef __attribute__((ext_vector_type(8))) __bf16 bf16x8;

typedef const __attribute__((address_space(1))) void* as1_t;
typedef __attribute__((address_space(3))) void*       as3_t;
#define GLOAD16(g, l) __builtin_amdgcn_global_load_lds((as1_t)(g), (as3_t)(l), 16, 0, 0)

__device__ __forceinline__ u16 f2b(float f) {
    unsigned u = __float_as_uint(f);
    u += 0x7FFFu + ((u >> 16) & 1u);        // RNE
    return (u16)(u >> 16);
}
__device__ __forceinline__ float b2f(u16 b) {
    return __uint_as_float(((unsigned)b) << 16);
}

// ---------------------------------------------------------------------------
// bf16 MFMA GEMM: C[M,N] = A[M,K] * Bt[N,K]^T (+bias, opt ReLU, opt +Cin)
// 128x128 tile, BK=32, 256 threads (4 waves, 2x2 of 64x64), 16x16x32 MFMA.
// A row-major stride K; Bt row-major stride K. M,N multiples of 128; K of 32.
// ---------------------------------------------------------------------------
template<int RELU, int ADDC, int OUTB>
__global__ __launch_bounds__(256, 2)
void gemm_bf16(const u16* __restrict__ A, const u16* __restrict__ Bt,
               const float* __restrict__ bias, void* __restrict__ Cout,
               const float* __restrict__ Cin, int ldc, int K)
{
    __shared__ u16 sA[128 * 32];
    __shared__ u16 sB[128 * 32];
    const int tid = threadIdx.x;
    const int w = tid >> 6, l = tid & 63;
    const int m0 = blockIdx.y * 128, n0 = blockIdx.x * 128;
    const int wr = (w >> 1) * 64, wc = (w & 1) * 64;

    // staging geometry: issue i covers elements [i*2048, i*2048+2048) of the
    // [128][32] tile; wave w stages 512 elems at LDS base w*512 (+i*2048);
    // lane's global element = i*2048 + w*512 + l*8.
    const int e0 = w * 512 + l * 8;
    const int r0 = e0 >> 5, c0 = e0 & 31;
    const int r1 = r0 + 64;

    const u16* gA0 = A + (size_t)(m0 + r0) * K + c0;
    const u16* gA1 = A + (size_t)(m0 + r1) * K + c0;
    const u16* gB0 = Bt + (size_t)(n0 + r0) * K + c0;
    const u16* gB1 = Bt + (size_t)(n0 + r1) * K + c0;
    u16* lA0 = sA + w * 512;
    u16* lA1 = sA + 2048 + w * 512;
    u16* lB0 = sB + w * 512;
    u16* lB1 = sB + 2048 + w * 512;

    f32x4 acc[4][4] = {};
    const int lr = l & 15, lk = (l >> 4) * 8;

    for (int k0 = 0; k0 < K; k0 += 32) {
        __syncthreads();                    // LDS reuse fence
        GLOAD16(gA0 + k0, lA0);
        GLOAD16(gA1 + k0, lA1);
        GLOAD16(gB0 + k0, lB0);
        GLOAD16(gB1 + k0, lB1);
        __syncthreads();                    // compiler drains vmcnt(0) here

        bf16x8 av[4], bv[4];
#pragma unroll
        for (int f = 0; f < 4; ++f) {
            av[f] = *(const bf16x8*)&sA[(wr + f * 16 + lr) * 32 + lk];
            bv[f] = *(const bf16x8*)&sB[(wc + f * 16 + lr) * 32 + lk];
        }
#pragma unroll
        for (int i = 0; i < 4; ++i)
#pragma unroll
            for (int j = 0; j < 4; ++j)
                acc[i][j] = __builtin_amdgcn_mfma_f32_16x16x32_bf16(
                    av[i], bv[j], acc[i][j], 0, 0, 0);
    }

    // epilogue: C/D layout col = lane&15, row = (lane>>4)*4 + reg  [m89/m91]
    const int cb = n0 + wc + lr;
    const int rb = m0 + wr + (l >> 4) * 4;
#pragma unroll
    for (int j = 0; j < 4; ++j) {
        const int c = cb + j * 16;
        const float bvv = bias[c];
#pragma unroll
        for (int i = 0; i < 4; ++i) {
#pragma unroll
            for (int r = 0; r < 4; ++r) {
                const size_t row = (size_t)(rb + i * 16 + r);
                float v = acc[i][j][r] + bvv;
                if (RELU) v = fmaxf(v, 0.f);
                if (ADDC) v += Cin[row * ldc + c];
                if (OUTB) ((u16*)Cout)[row * ldc + c] = f2b(v);
                else      ((float*)Cout)[row * ldc + c] = v;
            }
        }
    }
}

// ---------------------------------------------------------------------------
// transpose + f32->bf16: Wt[n*K + k] = bf16(W[k*N + n]); K,N multiples of 64
// ---------------------------------------------------------------------------
__global__ void k_transpose(const float* __restrict__ W, u16* __restrict__ Wt,
                            int K, int N)
{
    __shared__ float tile[64][65];
    const int k0 = blockIdx.y * 64, n0 = blockIdx.x * 64;
    const int tr = threadIdx.x >> 6, tc = threadIdx.x & 63;
    for (int rr = tr; rr < 64; rr += 4)
        tile[rr][tc] = W[(size_t)(k0 + rr) * N + n0 + tc];
    __syncthreads();
    for (int rr = tr; rr < 64; rr += 4)
        Wt[(size_t)(n0 + rr) * K + k0 + tc] = f2b(tile[tc][rr]);
}

// f32 -> bf16 elementwise (n multiple of 4)
__global__ void k_f2b4(const float4* __restrict__ in, ushort4* __restrict__ out,
                       int n4)
{
    int i = blockIdx.x * 256 + threadIdx.x;
    const int stride = gridDim.x * 256;
    for (; i < n4; i += stride) {
        float4 v = in[i];
        ushort4 o;
        o.x = f2b(v.x); o.y = f2b(v.y); o.z = f2b(v.z); o.w = f2b(v.w);
        out[i] = o;
    }
}

// softmax(logits) @ emb_dist -> cat1 cols [INCH, INCH+768)
__global__ void k_softmax_embed(const float* __restrict__ logits,
                                const float* __restrict__ embd,
                                u16* __restrict__ cat1)
{
    const int i = blockIdx.x;
    const int t = threadIdx.x;     // 256
    __shared__ float red[256];
    __shared__ float pr[NCLS];
    float v = (t < NCLS) ? logits[i * NCLS + t] : -3.4e38f;
    red[t] = v; __syncthreads();
    for (int s = 128; s > 0; s >>= 1) {
        if (t < s) red[t] = fmaxf(red[t], red[t + s]);
        __syncthreads();
    }
    const float mx = red[0]; __syncthreads();
    float e = (t < NCLS) ? expf(v - mx) : 0.f;
    red[t] = e; __syncthreads();
    for (int s = 128; s > 0; s >>= 1) {
        if (t < s) red[t] += red[t + s];
        __syncthreads();
    }
    const float inv = 1.f / red[0];
    if (t < NCLS) pr[t] = e * inv;
    __syncthreads();
    for (int j = t; j < EMB_; j += 256) {
        float s = 0.f;
        for (int k = 0; k < NCLS; ++k) s += pr[k] * embd[k * EMB_ + j];
        cat1[(size_t)i * 4992 + INCH + j] = f2b(s);
    }
}

// pos MLP: fc1 + BN + fc2 + relu -> cat1 cols [INCH+768, INCH+768+128)
__global__ void k_pos(const float* __restrict__ pos9, const float* __restrict__ w1,
                      const float* __restrict__ b1, const float* __restrict__ g,
                      const float* __restrict__ bb, const float* __restrict__ mu,
                      const float* __restrict__ var, const float* __restrict__ w2,
                      const float* __restrict__ b2, u16* __restrict__ cat1)
{
    const int i = blockIdx.x, t = threadIdx.x;   // 128
    __shared__ float pi[9];
    __shared__ float h[32];
    if (t < 9) pi[t] = pos9[i * 9 + t];
    __syncthreads();
    if (t < 32) {
        float s = b1[t];
        for (int k = 0; k < 9; ++k) s += pi[k] * w1[k * 32 + t];
        h[t] = (s - mu[t]) * rsqrtf(var[t] + 1e-5f) * g[t] + bb[t];
    }
    __syncthreads();
    float s = b2[t];
    for (int k = 0; k < 32; ++k) s += h[k] * w2[k * GEO_ + t];
    cat1[(size_t)i * 4992 + INCH + EMB_ + t] = f2b(fmaxf(s, 0.f));
}

// pack roi -> cat1[0:4096] and aaug[768:4864]; emb_label gather -> aaug[0:768]
__global__ void k_pack(const float* __restrict__ roi, const float* __restrict__ embl,
                       const int* __restrict__ labels, u16* __restrict__ cat1,
                       u16* __restrict__ aaug)
{
    const int i = blockIdx.x, t = threadIdx.x;   // 256
    const float* r = roi + (size_t)i * INCH;
    u16* c1 = cat1 + (size_t)i * 4992;
    u16* aa = aaug + (size_t)i * 5376;
    for (int c = t; c < INCH; c += 256) {
        u16 b = f2b(r[c]);
        c1[c] = b;
        aa[EMB_ + c] = b;
    }
    const float* el = embl + (size_t)labels[i] * EMB_;
    for (int c = t; c < EMB_; c += 256) aa[c] = f2b(el[c]);
}

// geo(32) from boxes + spt1 (K=32) + relu -> bf16 [8192,512]
__global__ void k_geo_spt1(const float* __restrict__ boxes, const int* __restrict__ ridx,
                           const float* __restrict__ w1, const float* __restrict__ b1,
                           u16* __restrict__ out)
{
    const int p = blockIdx.x;        // 0..8191
    const int t = threadIdx.x;       // 256
    const int b = p >> 9;
    __shared__ float geo[32];
    if (t == 0) {
        const int i0 = ridx[p * 2 + 0];
        const int i1 = ridx[p * 2 + 1];
        const float* x = boxes + (size_t)(b * O_ + i0) * 4;
        const float* y = boxes + (size_t)(b * O_ + i1) * 4;
        float a0 = x[0], a1 = x[1], a2 = x[2], a3 = x[3];
        float c0 = y[0], c1 = y[1], c2 = y[2], c3 = y[3];
        geo[0] = a0; geo[1] = a1; geo[2] = a2; geo[3] = a3;
        geo[4] = (a0 + a2) * 0.5f; geo[5] = (a1 + a3) * 0.5f;
        geo[6] = a2 - a0; geo[7] = a3 - a1;
        geo[8] = c0; geo[9] = c1; geo[10] = c2; geo[11] = c3;
        geo[12] = (c0 + c2) * 0.5f; geo[13] = (c1 + c3) * 0.5f;
        geo[14] = c2 - c0; geo[15] = c3 - c1;
        float u0 = fminf(a0, c0), u1 = fminf(a1, c1);
        float u2 = fmaxf(a2, c2), u3 = fmaxf(a3, c3);
        geo[16] = u0; geo[17] = u1; geo[18] = u2; geo[19] = u3;
        geo[20] = (u0 + u2) * 0.5f; geo[21] = (u1 + u3) * 0.5f;
        geo[22] = u2 - u0; geo[23] = u3 - u1;
        float q0 = fmaxf(a0, c0), q1 = fmaxf(a1, c1);
        float q2 = fminf(a2, c2), q3 = fminf(a3, c3);
        if (q0 <= q2 && q1 <= q3) {
            geo[24] = q0; geo[25] = q1; geo[26] = q2; geo[27] = q3;
            geo[28] = (q0 + q2) * 0.5f; geo[29] = (q1 + q3) * 0.5f;
            geo[30] = q2 - q0; geo[31] = q3 - q1;
        } else {
            for (int k = 24; k < 32; ++k) geo[k] = 0.f;
        }
    }
    __syncthreads();
    for (int j = t; j < HID_; j += 256) {
        float s = b1[j];
#pragma unroll
        for (int k = 0; k < 32; ++k) s += geo[k] * w1[k * HID_ + j];
        out[(size_t)p * HID_ + j] = f2b(fmaxf(s, 0.f));
    }
}

// pair gather from fused (bf16) * spt (f32) -> bf16 [8192,1024]
__global__ void k_pairmul(const u16* __restrict__ fused, const float* __restrict__ spt,
                          const int* __restrict__ ridx, u16* __restrict__ apair)
{
    const int idx = blockIdx.x * 256 + threadIdx.x;   // exactly 8192*1024
    const int p = idx >> 10, c = idx & 1023;
    const int b = p >> 9;
    const int part = c >> 9;
    const int ii = ridx[p * 2 + part];
    const float fv = b2f(fused[(size_t)(b * O_ + ii) * 1024 + c]);
    apair[idx] = f2b(fv * spt[idx]);
}

// ---------------------------------------------------------------------------
extern "C" void kernel_launch(void* const* d_in, const int* in_sizes, int n_in,
                              void* d_out, int out_size, void* d_ws, size_t ws_size,
                              hipStream_t stream)
{
    (void)in_sizes; (void)n_in; (void)out_size; (void)ws_size;
    const float* roi     = (const float*)d_in[0];
    const float* unionf  = (const float*)d_in[1];
    const float* logits  = (const float*)d_in[2];
    const float* pos9    = (const float*)d_in[3];
    const float* boxes   = (const float*)d_in[4];
    const int*   labels  = (const int*)d_in[5];
    const int*   relidx  = (const int*)d_in[6];
    const float* embd    = (const float*)d_in[7];
    const float* embl    = (const float*)d_in[8];
    const float* relup_w = (const float*)d_in[9];
    const float* relup_b = (const float*)d_in[10];
    const float* updim_w = (const float*)d_in[11];
    const float* updim_b = (const float*)d_in[12];
    const float* fc1w    = (const float*)d_in[13];
    const float* fc1b    = (const float*)d_in[14];
    const float* bng     = (const float*)d_in[15];
    const float* bnb     = (const float*)d_in[16];
    const float* bnm     = (const float*)d_in[17];
    const float* bnv     = (const float*)d_in[18];
    const float* fc2w    = (const float*)d_in[19];
    const float* fc2b    = (const float*)d_in[20];
    const float* spt1w   = (const float*)d_in[21];
    const float* spt1b   = (const float*)d_in[22];
    const float* spt2w   = (const float*)d_in[23];
    const float* spt2b   = (const float*)d_in[24];
    const float* finw    = (const float*)d_in[25];
    const float* finb    = (const float*)d_in[26];
    const float* objhw   = (const float*)d_in[27];
    const float* objhb   = (const float*)d_in[28];
    const float* augw    = (const float*)d_in[29];
    const float* augb    = (const float*)d_in[30];

    char* wp = (char*)d_ws;
    auto take = [&](size_t bytes) {
        char* r = wp; wp += (bytes + 255) & ~(size_t)255; return r;
    };
    u16* wtObj   = (u16*)take((size_t)512  * 4992 * 2);
    u16* wtUpd   = (u16*)take((size_t)1024 * 5376 * 2);
    u16* wtSpt2  = (u16*)take((size_t)1024 * 512  * 2);
    u16* wtFin   = (u16*)take((size_t)2048 * 1024 * 2);
    u16* wtRelup = (u16*)take((size_t)2048 * 4096 * 2);
    u16* wtAug   = (u16*)take((size_t)2048 * 5376 * 2);
    u16* aCat1   = (u16*)take((size_t)1280 * 4992 * 2);
    u16* aAug    = (u16*)take((size_t)1280 * 5376 * 2);
    u16* aUnion  = (u16*)take((size_t)8192 * 4096 * 2);
    u16* aSpt1   = (u16*)take((size_t)8192 * 512  * 2);
    u16* aPair   = (u16*)take((size_t)8192 * 1024 * 2);
    u16* fusedB  = (u16*)take((size_t)1280 * 1024 * 2);
    float* sptF  = (float*)take((size_t)8192 * 1024 * 4);

    float* outAug = (float*)d_out;                          // [1280,2048]
    float* outRel = (float*)d_out + (size_t)1280 * 2048;    // [8192,2048]

    // weights -> bf16 transposed (N x K)
    k_transpose<<<dim3(512 / 64, 4992 / 64), 256, 0, stream>>>(objhw,  wtObj,   4992, 512);
    k_transpose<<<dim3(1024 / 64, 5376 / 64), 256, 0, stream>>>(updim_w, wtUpd,  5376, 1024);
    k_transpose<<<dim3(1024 / 64, 512 / 64), 256, 0, stream>>>(spt2w,  wtSpt2,  512, 1024);
    k_transpose<<<dim3(2048 / 64, 1024 / 64), 256, 0, stream>>>(finw,   wtFin,   1024, 2048);
    k_transpose<<<dim3(2048 / 64, 4096 / 64), 256, 0, stream>>>(relup_w, wtRelup, 4096, 2048);
    k_transpose<<<dim3(2048 / 64, 5376 / 64), 256, 0, stream>>>(augw,   wtAug,   5376, 2048);

    // activations prep
    k_f2b4<<<2048, 256, 0, stream>>>((const float4*)unionf, (ushort4*)aUnion,
                                     (8192 * 4096) / 4);
    k_softmax_embed<<<1280, 256, 0, stream>>>(logits, embd, aCat1);
    k_pos<<<1280, 128, 0, stream>>>(pos9, fc1w, fc1b, bng, bnb, bnm, bnv, fc2w, fc2b, aCat1);
    k_pack<<<1280, 256, 0, stream>>>(roi, embl, labels, aCat1, aAug);

    // aug_hid = cat1 @ objhid (bf16 out into aAug cols [4864,5376))
    gemm_bf16<0, 0, 1><<<dim3(512 / 128, 1280 / 128), 256, 0, stream>>>(
        aCat1, wtObj, objhb, (void*)(aAug + 4864), nullptr, 5376, 4992);
    // fused = aAug @ updim (bf16)
    gemm_bf16<0, 0, 1><<<dim3(1024 / 128, 1280 / 128), 256, 0, stream>>>(
        aAug, wtUpd, updim_b, (void*)fusedB, nullptr, 1024, 5376);

    // geo + spt1
    k_geo_spt1<<<8192, 256, 0, stream>>>(boxes, relidx, spt1w, spt1b, aSpt1);
    // spt = relu(spt1out @ spt2) (f32)
    gemm_bf16<1, 0, 0><<<dim3(1024 / 128, 8192 / 128), 256, 0, stream>>>(
        aSpt1, wtSpt2, spt2b, (void*)sptF, nullptr, 1024, 512);
    // pair_feat = gather(fused) * spt (bf16)
    k_pairmul<<<(8192 * 1024) / 256, 256, 0, stream>>>(fusedB, sptF, relidx, aPair);

    // rel = relu(pair @ fin) -> outRel (f32)
    gemm_bf16<1, 0, 0><<<dim3(2048 / 128, 8192 / 128), 256, 0, stream>>>(
        aPair, wtFin, finb, (void*)outRel, nullptr, 2048, 1024);
    // rel_features = union @ relup + relup_b + rel  (C-add epilogue)
    gemm_bf16<0, 1, 0><<<dim3(2048 / 128, 8192 / 128), 256, 0, stream>>>(
        aUnion, wtRelup, relup_b, (void*)outRel, outRel, 2048, 4096);
    // augment_out = relu(aAug @ aug_w) -> outAug (f32)
    gemm_bf16<1, 0, 0><<<dim3(2048 / 128, 1280 / 128), 256, 0, stream>>>(
        aAug, wtAug, augb, (void*)outAug, nullptr, 2048, 5376);
}

// Round 2
// 772.491 us; speedup vs baseline: 1.0585x; 1.0585x over previous
//
#include <hip/hip_runtime.h>
#include <hip/hip_bf16.h>

#define B_    16
#define O_    80
#define R_    512
#define INCH  4096
#define NCLS  151
#define EMB_  768
#define HID_  512
#define POOL_ 2048
#define GEO_  128

typedef unsigned short u16;
typedef __attribute__((ext_vector_type(4))) float  f32x4;
typedef __attribute__((ext_vector_type(8))) __bf16 bf16x8;

typedef const __attribute__((address_space(1))) void* as1_t;
typedef __attribute__((address_space(3))) void*       as3_t;
#define GLOAD16(g, l) __builtin_amdgcn_global_load_lds((as1_t)(g), (as3_t)(l), 16, 0, 0)

__device__ __forceinline__ u16 f2b(float f) {
    unsigned u = __float_as_uint(f);
    u += 0x7FFFu + ((u >> 16) & 1u);        // RNE
    return (u16)(u >> 16);
}
__device__ __forceinline__ float b2f(u16 b) {
    return __uint_as_float(((unsigned)b) << 16);
}

// ===========================================================================
// 256x256-tile pipelined bf16 GEMM (T2 swizzle + T3/T4 counted vmcnt + T5).
// C[M,N](f32) = relu?(seg1) chained with seg2, both A[M,K]*Bt[N,K]^T.
//   MIDRELU: after seg1's K, acc = relu(acc + bias1[col]); seg2 accumulates on.
//   End: acc += bias2[col]; ENDRELU applies relu; store f32.
// BK=32, 512 thr (8 waves 2Mx4N), per-wave C 128x64, LDS 2 x 32KB buffers.
// LDS layout (A and B each 16KB/buffer): phys row p(0..127) x 8 16B-slots.
//   logical (row r<256, k<32): p=r&127, s_log=(r>>7)*4+(k>>3),
//   s_phys = s_log ^ (p&7)  -> conflict-free ds_read_b128 (8-slot spread).
// global_load_lds writes linearly; source is pre-swizzled (m173 pattern).
// Staging (region-ordered, race-free with 2 buffers):
//   regions: A0=phys rows 0-63 (read ph0), A1=rows 64-127 (ph1),
//            B0,B1 (read ph0; B frags reg-cached for ph1).
//   ph0 of tile t: stage A1(t+1); ph1: stage A0,B0,B1(t+2).
//   vmcnt(4) at every phase end (vmcnt(0) for last 2 tiles), then s_barrier.
// ===========================================================================
template<int MIDRELU, int ENDRELU>
__global__ __launch_bounds__(512, 2)
void gemm256(const u16* __restrict__ A1, int lda1, const u16* __restrict__ B1,
             int ldb1, int nt1,
             const u16* __restrict__ A2, int lda2, const u16* __restrict__ B2,
             int ldb2, int nt2,
             const float* __restrict__ bias1, const float* __restrict__ bias2,
             float* __restrict__ C, int ldc, int NBN)
{
    __shared__ u16 lds[2][16384];           // 2 x (A 8192 + B 8192) elems

    const int tid = threadIdx.x;
    const int w = tid >> 6, l = tid & 63;
    const int wm = w >> 2, wn = w & 3;
    const int NT = nt1 + nt2;

    // XCD-aware block swizzle (gridDim.x % 8 == 0 for all our launches)
    const int nwg = gridDim.x;
    const int cpx = nwg >> 3;
    const int wg = (blockIdx.x & 7) * cpx + (blockIdx.x >> 3);
    const int mb = wg / NBN, nb = wg % NBN;
    const int m0 = mb * 256, n0 = nb * 256;

    // ---- staging constants (pre-swizzled global source) ----
    // thread covers chunk byte o = tid*16: pr=tid>>3, s_phys=tid&7
    const int sl    = (tid & 7) ^ ((tid >> 3) & 7);          // s_log
    const int rowlo = (tid >> 3) + ((sl >> 2) << 7);         // logical row (lo chunk)
    const int koff  = (sl & 3) << 3;                         // k element offset

    auto stage = [&](int tt, int c, int bsel2) {             // c: 0=A0 1=A1 2=B0 3=B1
        const bool isA = (c < 2);
        const u16* base; int ld, k0;
        if (tt < nt1) { base = isA ? A1 : B1; ld = isA ? lda1 : ldb1; k0 = tt * 32; }
        else          { base = isA ? A2 : B2; ld = isA ? lda2 : ldb2; k0 = (tt - nt1) * 32; }
        const int x0 = isA ? m0 : n0;
        const int row = rowlo + ((c & 1) << 6);
        const u16* src = base + (size_t)(x0 + row) * ld + k0 + koff;
        u16* dst = &lds[bsel2][(isA ? 0 : 8192) + ((c & 1) << 12) + (w << 9)];
        GLOAD16(src, dst);
    };

    // ---- fragment read offsets (swizzled) ----
    const int lr = l & 15, kq = l >> 4;
    const int offA = lr * 64 + (((wm << 2) | kq) ^ (lr & 7)) * 8;            // + mq*4096 + f*1024
    const int offB = 8192 + ((wn & 1) << 12) + lr * 64
                   + ((((wn >> 1) << 2) | kq) ^ (lr & 7)) * 8;               // + fr*1024

    f32x4 acc[8][4] = {};

    // ---- prologue ----
    stage(0, 0, 0); stage(0, 1, 0); stage(0, 2, 0); stage(0, 3, 0);
    asm volatile("s_waitcnt vmcnt(0)" ::: "memory");
    stage(1, 0, 1); stage(1, 2, 1); stage(1, 3, 1);
    asm volatile("s_barrier" ::: "memory");

    int bsel = 0;
    for (int t = 0; t < NT; ++t, bsel ^= 1) {
        const u16* bufc = &lds[bsel][0];
        bf16x8 av[4], bv[4];

        // ================= phase 0 (mq = 0) =================
#pragma unroll
        for (int fr = 0; fr < 4; ++fr)
            bv[fr] = *(const bf16x8*)(bufc + offB + fr * 1024);
#pragma unroll
        for (int f = 0; f < 4; ++f)
            av[f] = *(const bf16x8*)(bufc + offA + f * 1024);
        if (t + 1 < NT) stage(t + 1, 1, bsel ^ 1);
        asm volatile("s_barrier" ::: "memory");
        __builtin_amdgcn_s_setprio(1);
#pragma unroll
        for (int f = 0; f < 4; ++f)
#pragma unroll
            for (int j = 0; j < 4; ++j)
                acc[f][j] = __builtin_amdgcn_mfma_f32_16x16x32_bf16(
                    av[f], bv[j], acc[f][j], 0, 0, 0);
        __builtin_amdgcn_s_setprio(0);
        if (t < NT - 2) asm volatile("s_waitcnt vmcnt(4)" ::: "memory");
        else            asm volatile("s_waitcnt vmcnt(0)" ::: "memory");
        asm volatile("s_barrier" ::: "memory");

        // ================= phase 1 (mq = 1) =================
#pragma unroll
        for (int f = 0; f < 4; ++f)
            av[f] = *(const bf16x8*)(bufc + offA + 4096 + f * 1024);
        if (t + 2 < NT) { stage(t + 2, 0, bsel); stage(t + 2, 2, bsel); stage(t + 2, 3, bsel); }
        asm volatile("s_barrier" ::: "memory");
        __builtin_amdgcn_s_setprio(1);
#pragma unroll
        for (int f = 0; f < 4; ++f)
#pragma unroll
            for (int j = 0; j < 4; ++j)
                acc[4 + f][j] = __builtin_amdgcn_mfma_f32_16x16x32_bf16(
                    av[f], bv[j], acc[4 + f][j], 0, 0, 0);
        __builtin_amdgcn_s_setprio(0);
        if (t < NT - 2) asm volatile("s_waitcnt vmcnt(4)" ::: "memory");
        else            asm volatile("s_waitcnt vmcnt(0)" ::: "memory");
        asm volatile("s_barrier" ::: "memory");

        // segment boundary: acc = relu(acc + bias1)
        if (MIDRELU && t == nt1 - 1) {
#pragma unroll
            for (int j = 0; j < 4; ++j) {
                const float bb = bias1[n0 + wn * 64 + j * 16 + lr];
#pragma unroll
                for (int i = 0; i < 8; ++i)
#pragma unroll
                    for (int r = 0; r < 4; ++r)
                        acc[i][j][r] = fmaxf(acc[i][j][r] + bb, 0.f);
            }
        }
    }

    // ---- epilogue (C/D layout: col=lane&15, row=(lane>>4)*4+reg) ----
    const int cb = n0 + wn * 64 + lr;
    const int rb = m0 + wm * 128 + kq * 4;
#pragma unroll
    for (int j = 0; j < 4; ++j) {
        const int col = cb + j * 16;
        const float bv2 = bias2[col];
#pragma unroll
        for (int i = 0; i < 8; ++i)
#pragma unroll
            for (int r = 0; r < 4; ++r) {
                float v = acc[i][j][r] + bv2;
                if (ENDRELU) v = fmaxf(v, 0.f);
                C[(size_t)(rb + i * 16 + r) * ldc + col] = v;
            }
    }
}

// ---------------------------------------------------------------------------
// bf16 MFMA GEMM (m97-class): C = A * Bt^T (+bias, opt ReLU, opt bf16 out)
// 128x128 tile, BK=32, 256 threads. Used for the small-M (1280-row) GEMMs.
// ---------------------------------------------------------------------------
template<int RELU, int ADDC, int OUTB>
__global__ __launch_bounds__(256, 2)
void gemm_bf16(const u16* __restrict__ A, const u16* __restrict__ Bt,
               const float* __restrict__ bias, void* __restrict__ Cout,
               const float* __restrict__ Cin, int ldc, int K)
{
    __shared__ u16 sA[128 * 32];
    __shared__ u16 sB[128 * 32];
    const int tid = threadIdx.x;
    const int w = tid >> 6, l = tid & 63;
    const int m0 = blockIdx.y * 128, n0 = blockIdx.x * 128;
    const int wr = (w >> 1) * 64, wc = (w & 1) * 64;

    const int e0 = w * 512 + l * 8;
    const int r0 = e0 >> 5, c0 = e0 & 31;
    const int r1 = r0 + 64;

    const u16* gA0 = A + (size_t)(m0 + r0) * K + c0;
    const u16* gA1 = A + (size_t)(m0 + r1) * K + c0;
    const u16* gB0 = Bt + (size_t)(n0 + r0) * K + c0;
    const u16* gB1 = Bt + (size_t)(n0 + r1) * K + c0;
    u16* lA0 = sA + w * 512;
    u16* lA1 = sA + 2048 + w * 512;
    u16* lB0 = sB + w * 512;
    u16* lB1 = sB + 2048 + w * 512;

    f32x4 acc[4][4] = {};
    const int lr = l & 15, lk = (l >> 4) * 8;

    for (int k0 = 0; k0 < K; k0 += 32) {
        __syncthreads();
        GLOAD16(gA0 + k0, lA0);
        GLOAD16(gA1 + k0, lA1);
        GLOAD16(gB0 + k0, lB0);
        GLOAD16(gB1 + k0, lB1);
        __syncthreads();

        bf16x8 av[4], bv[4];
#pragma unroll
        for (int f = 0; f < 4; ++f) {
            av[f] = *(const bf16x8*)&sA[(wr + f * 16 + lr) * 32 + lk];
            bv[f] = *(const bf16x8*)&sB[(wc + f * 16 + lr) * 32 + lk];
        }
#pragma unroll
        for (int i = 0; i < 4; ++i)
#pragma unroll
            for (int j = 0; j < 4; ++j)
                acc[i][j] = __builtin_amdgcn_mfma_f32_16x16x32_bf16(
                    av[i], bv[j], acc[i][j], 0, 0, 0);
    }

    const int cb = n0 + wc + lr;
    const int rb = m0 + wr + (l >> 4) * 4;
#pragma unroll
    for (int j = 0; j < 4; ++j) {
        const int c = cb + j * 16;
        const float bvv = bias[c];
#pragma unroll
        for (int i = 0; i < 4; ++i) {
#pragma unroll
            for (int r = 0; r < 4; ++r) {
                const size_t row = (size_t)(rb + i * 16 + r);
                float v = acc[i][j][r] + bvv;
                if (RELU) v = fmaxf(v, 0.f);
                if (ADDC) v += Cin[row * ldc + c];
                if (OUTB) ((u16*)Cout)[row * ldc + c] = f2b(v);
                else      ((float*)Cout)[row * ldc + c] = v;
            }
        }
    }
}

// ---------------------------------------------------------------------------
// transpose + f32->bf16: Wt[n*K + k] = bf16(W[k*N + n]); K,N multiples of 64
// ---------------------------------------------------------------------------
__global__ void k_transpose(const float* __restrict__ W, u16* __restrict__ Wt,
                            int K, int N)
{
    __shared__ float tile[64][65];
    const int k0 = blockIdx.y * 64, n0 = blockIdx.x * 64;
    const int tr = threadIdx.x >> 6, tc = threadIdx.x & 63;
    for (int rr = tr; rr < 64; rr += 4)
        tile[rr][tc] = W[(size_t)(k0 + rr) * N + n0 + tc];
    __syncthreads();
    for (int rr = tr; rr < 64; rr += 4)
        Wt[(size_t)(n0 + rr) * K + k0 + tc] = f2b(tile[tc][rr]);
}

// f32 -> bf16 elementwise (n multiple of 4)
__global__ void k_f2b4(const float4* __restrict__ in, ushort4* __restrict__ out,
                       int n4)
{
    int i = blockIdx.x * 256 + threadIdx.x;
    const int stride = gridDim.x * 256;
    for (; i < n4; i += stride) {
        float4 v = in[i];
        ushort4 o;
        o.x = f2b(v.x); o.y = f2b(v.y); o.z = f2b(v.z); o.w = f2b(v.w);
        out[i] = o;
    }
}

// softmax(logits) @ emb_dist -> cat1 cols [INCH, INCH+768)
__global__ void k_softmax_embed(const float* __restrict__ logits,
                                const float* __restrict__ embd,
                                u16* __restrict__ cat1)
{
    const int i = blockIdx.x;
    const int t = threadIdx.x;     // 256
    __shared__ float red[256];
    __shared__ float pr[NCLS];
    float v = (t < NCLS) ? logits[i * NCLS + t] : -3.4e38f;
    red[t] = v; __syncthreads();
    for (int s = 128; s > 0; s >>= 1) {
        if (t < s) red[t] = fmaxf(red[t], red[t + s]);
        __syncthreads();
    }
    const float mx = red[0]; __syncthreads();
    float e = (t < NCLS) ? expf(v - mx) : 0.f;
    red[t] = e; __syncthreads();
    for (int s = 128; s > 0; s >>= 1) {
        if (t < s) red[t] += red[t + s];
        __syncthreads();
    }
    const float inv = 1.f / red[0];
    if (t < NCLS) pr[t] = e * inv;
    __syncthreads();
    for (int j = t; j < EMB_; j += 256) {
        float s = 0.f;
        for (int k = 0; k < NCLS; ++k) s += pr[k] * embd[k * EMB_ + j];
        cat1[(size_t)i * 4992 + INCH + j] = f2b(s);
    }
}

// pos MLP: fc1 + BN + fc2 + relu -> cat1 cols [INCH+768, INCH+768+128)
__global__ void k_pos(const float* __restrict__ pos9, const float* __restrict__ w1,
                      const float* __restrict__ b1, const float* __restrict__ g,
                      const float* __restrict__ bb, const float* __restrict__ mu,
                      const float* __restrict__ var, const float* __restrict__ w2,
                      const float* __restrict__ b2, u16* __restrict__ cat1)
{
    const int i = blockIdx.x, t = threadIdx.x;   // 128
    __shared__ float pi[9];
    __shared__ float h[32];
    if (t < 9) pi[t] = pos9[i * 9 + t];
    __syncthreads();
    if (t < 32) {
        float s = b1[t];
        for (int k = 0; k < 9; ++k) s += pi[k] * w1[k * 32 + t];
        h[t] = (s - mu[t]) * rsqrtf(var[t] + 1e-5f) * g[t] + bb[t];
    }
    __syncthreads();
    float s = b2[t];
    for (int k = 0; k < 32; ++k) s += h[k] * w2[k * GEO_ + t];
    cat1[(size_t)i * 4992 + INCH + EMB_ + t] = f2b(fmaxf(s, 0.f));
}

// pack roi -> cat1[0:4096] and aaug[768:4864]; emb_label gather -> aaug[0:768]
__global__ void k_pack(const float* __restrict__ roi, const float* __restrict__ embl,
                       const int* __restrict__ labels, u16* __restrict__ cat1,
                       u16* __restrict__ aaug)
{
    const int i = blockIdx.x, t = threadIdx.x;   // 256
    const float* r = roi + (size_t)i * INCH;
    u16* c1 = cat1 + (size_t)i * 4992;
    u16* aa = aaug + (size_t)i * 5376;
    for (int c = t; c < INCH; c += 256) {
        u16 b = f2b(r[c]);
        c1[c] = b;
        aa[EMB_ + c] = b;
    }
    const float* el = embl + (size_t)labels[i] * EMB_;
    for (int c = t; c < EMB_; c += 256) aa[c] = f2b(el[c]);
}

// geo(32) from boxes + spt1 (K=32) + relu -> bf16 [8192,512]
__global__ void k_geo_spt1(const float* __restrict__ boxes, const int* __restrict__ ridx,
                           const float* __restrict__ w1, const float* __restrict__ b1,
                           u16* __restrict__ out)
{
    const int p = blockIdx.x;        // 0..8191
    const int t = threadIdx.x;       // 256
    const int b = p >> 9;
    __shared__ float geo[32];
    if (t == 0) {
        const int i0 = ridx[p * 2 + 0];
        const int i1 = ridx[p * 2 + 1];
        const float* x = boxes + (size_t)(b * O_ + i0) * 4;
        const float* y = boxes + (size_t)(b * O_ + i1) * 4;
        float a0 = x[0], a1 = x[1], a2 = x[2], a3 = x[3];
        float c0 = y[0], c1 = y[1], c2 = y[2], c3 = y[3];
        geo[0] = a0; geo[1] = a1; geo[2] = a2; geo[3] = a3;
        geo[4] = (a0 + a2) * 0.5f; geo[5] = (a1 + a3) * 0.5f;
        geo[6] = a2 - a0; geo[7] = a3 - a1;
        geo[8] = c0; geo[9] = c1; geo[10] = c2; geo[11] = c3;
        geo[12] = (c0 + c2) * 0.5f; geo[13] = (c1 + c3) * 0.5f;
        geo[14] = c2 - c0; geo[15] = c3 - c1;
        float u0 = fminf(a0, c0), u1 = fminf(a1, c1);
        float u2 = fmaxf(a2, c2), u3 = fmaxf(a3, c3);
        geo[16] = u0; geo[17] = u1; geo[18] = u2; geo[19] = u3;
        geo[20] = (u0 + u2) * 0.5f; geo[21] = (u1 + u3) * 0.5f;
        geo[22] = u2 - u0; geo[23] = u3 - u1;
        float q0 = fmaxf(a0, c0), q1 = fmaxf(a1, c1);
        float q2 = fminf(a2, c2), q3 = fminf(a3, c3);
        if (q0 <= q2 && q1 <= q3) {
            geo[24] = q0; geo[25] = q1; geo[26] = q2; geo[27] = q3;
            geo[28] = (q0 + q2) * 0.5f; geo[29] = (q1 + q3) * 0.5f;
            geo[30] = q2 - q0; geo[31] = q3 - q1;
        } else {
            for (int k = 24; k < 32; ++k) geo[k] = 0.f;
        }
    }
    __syncthreads();
    for (int j = t; j < HID_; j += 256) {
        float s = b1[j];
#pragma unroll
        for (int k = 0; k < 32; ++k) s += geo[k] * w1[k * HID_ + j];
        out[(size_t)p * HID_ + j] = f2b(fmaxf(s, 0.f));
    }
}

// pair gather from fused (bf16) * spt (f32) -> bf16 [8192,1024]
__global__ void k_pairmul(const u16* __restrict__ fused, const float* __restrict__ spt,
                          const int* __restrict__ ridx, u16* __restrict__ apair)
{
    const int idx = blockIdx.x * 256 + threadIdx.x;   // exactly 8192*1024
    const int p = idx >> 10, c = idx & 1023;
    const int b = p >> 9;
    const int part = c >> 9;
    const int ii = ridx[p * 2 + part];
    const float fv = b2f(fused[(size_t)(b * O_ + ii) * 1024 + c]);
    apair[idx] = f2b(fv * spt[idx]);
}

// ---------------------------------------------------------------------------
extern "C" void kernel_launch(void* const* d_in, const int* in_sizes, int n_in,
                              void* d_out, int out_size, void* d_ws, size_t ws_size,
                              hipStream_t stream)
{
    (void)in_sizes; (void)n_in; (void)out_size; (void)ws_size;
    const float* roi     = (const float*)d_in[0];
    const float* unionf  = (const float*)d_in[1];
    const float* logits  = (const float*)d_in[2];
    const float* pos9    = (const float*)d_in[3];
    const float* boxes   = (const float*)d_in[4];
    const int*   labels  = (const int*)d_in[5];
    const int*   relidx  = (const int*)d_in[6];
    const float* embd    = (const float*)d_in[7];
    const float* embl    = (const float*)d_in[8];
    const float* relup_w = (const float*)d_in[9];
    const float* relup_b = (const float*)d_in[10];
    const float* updim_w = (const float*)d_in[11];
    const float* updim_b = (const float*)d_in[12];
    const float* fc1w    = (const float*)d_in[13];
    const float* fc1b    = (const float*)d_in[14];
    const float* bng     = (const float*)d_in[15];
    const float* bnb     = (const float*)d_in[16];
    const float* bnm     = (const float*)d_in[17];
    const float* bnv     = (const float*)d_in[18];
    const float* fc2w    = (const float*)d_in[19];
    const float* fc2b    = (const float*)d_in[20];
    const float* spt1w   = (const float*)d_in[21];
    const float* spt1b   = (const float*)d_in[22];
    const float* spt2w   = (const float*)d_in[23];
    const float* spt2b   = (const float*)d_in[24];
    const float* finw    = (const float*)d_in[25];
    const float* finb    = (const float*)d_in[26];
    const float* objhw   = (const float*)d_in[27];
    const float* objhb   = (const float*)d_in[28];
    const float* augw    = (const float*)d_in[29];
    const float* augb    = (const float*)d_in[30];

    char* wp = (char*)d_ws;
    auto take = [&](size_t bytes) {
        char* r = wp; wp += (bytes + 255) & ~(size_t)255; return r;
    };
    u16* wtObj   = (u16*)take((size_t)512  * 4992 * 2);
    u16* wtUpd   = (u16*)take((size_t)1024 * 5376 * 2);
    u16* wtSpt2  = (u16*)take((size_t)1024 * 512  * 2);
    u16* wtFin   = (u16*)take((size_t)2048 * 1024 * 2);
    u16* wtRelup = (u16*)take((size_t)2048 * 4096 * 2);
    u16* wtAug   = (u16*)take((size_t)2048 * 5376 * 2);
    u16* aCat1   = (u16*)take((size_t)1280 * 4992 * 2);
    u16* aAug    = (u16*)take((size_t)1280 * 5376 * 2);
    u16* aUnion  = (u16*)take((size_t)8192 * 4096 * 2);
    u16* aSpt1   = (u16*)take((size_t)8192 * 512  * 2);
    u16* aPair   = (u16*)take((size_t)8192 * 1024 * 2);
    u16* fusedB  = (u16*)take((size_t)1280 * 1024 * 2);
    float* sptF  = (float*)take((size_t)8192 * 1024 * 4);

    float* outAug = (float*)d_out;                          // [1280,2048]
    float* outRel = (float*)d_out + (size_t)1280 * 2048;    // [8192,2048]

    // weights -> bf16 transposed (N x K)
    k_transpose<<<dim3(512 / 64, 4992 / 64), 256, 0, stream>>>(objhw,  wtObj,   4992, 512);
    k_transpose<<<dim3(1024 / 64, 5376 / 64), 256, 0, stream>>>(updim_w, wtUpd,  5376, 1024);
    k_transpose<<<dim3(1024 / 64, 512 / 64), 256, 0, stream>>>(spt2w,  wtSpt2,  512, 1024);
    k_transpose<<<dim3(2048 / 64, 1024 / 64), 256, 0, stream>>>(finw,   wtFin,   1024, 2048);
    k_transpose<<<dim3(2048 / 64, 4096 / 64), 256, 0, stream>>>(relup_w, wtRelup, 4096, 2048);
    k_transpose<<<dim3(2048 / 64, 5376 / 64), 256, 0, stream>>>(augw,   wtAug,   5376, 2048);

    // activations prep
    k_f2b4<<<2048, 256, 0, stream>>>((const float4*)unionf, (ushort4*)aUnion,
                                     (8192 * 4096) / 4);
    k_softmax_embed<<<1280, 256, 0, stream>>>(logits, embd, aCat1);
    k_pos<<<1280, 128, 0, stream>>>(pos9, fc1w, fc1b, bng, bnb, bnm, bnv, fc2w, fc2b, aCat1);
    k_pack<<<1280, 256, 0, stream>>>(roi, embl, labels, aCat1, aAug);

    // aug_hid = cat1 @ objhid (bf16 out into aAug cols [4864,5376))
    gemm_bf16<0, 0, 1><<<dim3(512 / 128, 1280 / 128), 256, 0, stream>>>(
        aCat1, wtObj, objhb, (void*)(aAug + 4864), nullptr, 5376, 4992);
    // fused = aAug @ updim (bf16)
    gemm_bf16<0, 0, 1><<<dim3(1024 / 128, 1280 / 128), 256, 0, stream>>>(
        aAug, wtUpd, updim_b, (void*)fusedB, nullptr, 1024, 5376);

    // geo + spt1
    k_geo_spt1<<<8192, 256, 0, stream>>>(boxes, relidx, spt1w, spt1b, aSpt1);
    // spt = relu(spt1out @ spt2 + b) (f32) via pipelined 256^2 kernel
    gemm256<0, 1><<<dim3(128), 512, 0, stream>>>(
        aSpt1, 512, wtSpt2, 512, 16,
        aSpt1, 512, wtSpt2, 512, 0,
        spt2b, spt2b, sptF, 1024, 4);
    // pair_feat = gather(fused) * spt (bf16)
    k_pairmul<<<(8192 * 1024) / 256, 256, 0, stream>>>(fusedB, sptF, relidx, aPair);

    // rel_features = relu(pair@fin + finb) + union@relup + relup_b  (fused)
    gemm256<1, 0><<<dim3(256), 512, 0, stream>>>(
        aPair, 1024, wtFin, 1024, 32,
        aUnion, 4096, wtRelup, 4096, 128,
        finb, relup_b, outRel, 2048, 8);

    // augment_out = relu(aAug @ aug_w) -> outAug (f32)
    gemm_bf16<1, 0, 0><<<dim3(2048 / 128, 1280 / 128), 256, 0, stream>>>(
        aAug, wtAug, augb, (void*)outAug, nullptr, 2048, 5376);
}

// Round 3
// 545.623 us; speedup vs baseline: 1.4986x; 1.4158x over previous
//
#include <hip/hip_runtime.h>
#include <hip/hip_bf16.h>

#define B_    16
#define O_    80
#define R_    512
#define INCH  4096
#define NCLS  151
#define EMB_  768
#define HID_  512
#define POOL_ 2048
#define GEO_  128

typedef unsigned short u16;
typedef __attribute__((ext_vector_type(4))) float  f32x4;
typedef __attribute__((ext_vector_type(8))) __bf16 bf16x8;

typedef const __attribute__((address_space(1))) void* as1_t;
typedef __attribute__((address_space(3))) void*       as3_t;
#define GLOAD16(g, l) __builtin_amdgcn_global_load_lds((as1_t)(g), (as3_t)(l), 16, 0, 0)

__device__ __forceinline__ u16 f2b(float f) {
    unsigned u = __float_as_uint(f);
    u += 0x7FFFu + ((u >> 16) & 1u);        // RNE
    return (u16)(u >> 16);
}
__device__ __forceinline__ float b2f(u16 b) {
    return __uint_as_float(((unsigned)b) << 16);
}

// ===========================================================================
// 256x256-tile pipelined bf16 GEMM (T2 swizzle + T3/T4 counted vmcnt + T5).
// C[M,N](f32) = relu?(seg1) chained with seg2, both A[M,K]*Bt[N,K]^T.
// See round-2 comments for layout; this round: per-region hoisted source
// pointers (+64B/tile) instead of per-stage 64-bit address recompute.
// ===========================================================================
template<int MIDRELU, int ENDRELU>
__global__ __launch_bounds__(512, 2)
void gemm256(const u16* __restrict__ A1i, int lda1, const u16* __restrict__ B1i,
             int ldb1, int nt1,
             const u16* __restrict__ A2i, int lda2, const u16* __restrict__ B2i,
             int ldb2, int nt2,
             const float* __restrict__ bias1, const float* __restrict__ bias2,
             float* __restrict__ C, int ldc, int NBN)
{
    __shared__ u16 lds[2][16384];           // 2 x (A 8192 + B 8192) elems

    const int tid = threadIdx.x;
    const int w = tid >> 6, l = tid & 63;
    const int wm = w >> 2, wn = w & 3;
    const int NT = nt1 + nt2;

    const int nwg = gridDim.x;
    const int cpx = nwg >> 3;
    const int wg = (blockIdx.x & 7) * cpx + (blockIdx.x >> 3);
    const int mb = wg / NBN, nb = wg % NBN;
    const int m0 = mb * 256, n0 = nb * 256;

    // staging lane geometry (pre-swizzled global source, linear LDS dest)
    const int sl    = (tid & 7) ^ ((tid >> 3) & 7);          // s_log
    const int rowlo = (tid >> 3) + ((sl >> 2) << 7);         // logical row (lo)
    const int koff  = (sl & 3) << 3;

    // per-region source pointers, advance 32 elems (=64B) per staged tile
    const u16* pA0 = A1i + (size_t)(m0 + rowlo) * lda1 + koff;
    const u16* pA1 = A1i + (size_t)(m0 + rowlo + 64) * lda1 + koff;
    const u16* pB0 = B1i + (size_t)(n0 + rowlo) * ldb1 + koff;
    const u16* pB1 = B1i + (size_t)(n0 + rowlo + 64) * ldb1 + koff;

    u16* const lds0 = &lds[0][0];
    u16* const lds1 = &lds[1][0];
    const int wo = w << 9;

    // fragment read offsets (swizzled)
    const int lr = l & 15, kq = l >> 4;
    const int offA = lr * 64 + (((wm << 2) | kq) ^ (lr & 7)) * 8;
    const int offB = 8192 + ((wn & 1) << 12) + lr * 64
                   + ((((wn >> 1) << 2) | kq) ^ (lr & 7)) * 8;

    f32x4 acc[8][4] = {};

    // ---- prologue: tile0 all regions -> buf0; tile1 A0,B0,B1 -> buf1 ----
    GLOAD16(pA0, lds0 + wo);          pA0 += 32;
    GLOAD16(pA1, lds0 + 4096 + wo);   pA1 += 32;
    GLOAD16(pB0, lds0 + 8192 + wo);   pB0 += 32;
    GLOAD16(pB1, lds0 + 12288 + wo);  pB1 += 32;
    asm volatile("s_waitcnt vmcnt(0)" ::: "memory");
    GLOAD16(pA0, lds1 + wo);          pA0 += 32;
    GLOAD16(pB0, lds1 + 8192 + wo);   pB0 += 32;
    GLOAD16(pB1, lds1 + 12288 + wo);  pB1 += 32;
    asm volatile("s_barrier" ::: "memory");

    int bsel = 0;
    for (int t = 0; t < NT; ++t, bsel ^= 1) {
        u16* const bufc = bsel ? lds1 : lds0;
        u16* const bufo = bsel ? lds0 : lds1;
        bf16x8 av[4], bv[4];

        // ================= phase 0 (mq = 0) =================
#pragma unroll
        for (int fr = 0; fr < 4; ++fr)
            bv[fr] = *(const bf16x8*)(bufc + offB + fr * 1024);
#pragma unroll
        for (int f = 0; f < 4; ++f)
            av[f] = *(const bf16x8*)(bufc + offA + f * 1024);
        if (t + 1 < NT) {
            if (t + 1 == nt1)
                pA1 = A2i + (size_t)(m0 + rowlo + 64) * lda2 + koff;
            GLOAD16(pA1, bufo + 4096 + wo);  pA1 += 32;
        }
        asm volatile("s_barrier" ::: "memory");
        __builtin_amdgcn_s_setprio(1);
#pragma unroll
        for (int f = 0; f < 4; ++f)
#pragma unroll
            for (int j = 0; j < 4; ++j)
                acc[f][j] = __builtin_amdgcn_mfma_f32_16x16x32_bf16(
                    av[f], bv[j], acc[f][j], 0, 0, 0);
        __builtin_amdgcn_s_setprio(0);
        if (t < NT - 2) asm volatile("s_waitcnt vmcnt(4)" ::: "memory");
        else            asm volatile("s_waitcnt vmcnt(0)" ::: "memory");
        asm volatile("s_barrier" ::: "memory");

        // ================= phase 1 (mq = 1) =================
#pragma unroll
        for (int f = 0; f < 4; ++f)
            av[f] = *(const bf16x8*)(bufc + offA + 4096 + f * 1024);
        if (t + 2 < NT) {
            if (t + 2 == nt1) {
                pA0 = A2i + (size_t)(m0 + rowlo) * lda2 + koff;
                pB0 = B2i + (size_t)(n0 + rowlo) * ldb2 + koff;
                pB1 = B2i + (size_t)(n0 + rowlo + 64) * ldb2 + koff;
            }
            GLOAD16(pA0, bufc + wo);          pA0 += 32;
            GLOAD16(pB0, bufc + 8192 + wo);   pB0 += 32;
            GLOAD16(pB1, bufc + 12288 + wo);  pB1 += 32;
        }
        asm volatile("s_barrier" ::: "memory");
        __builtin_amdgcn_s_setprio(1);
#pragma unroll
        for (int f = 0; f < 4; ++f)
#pragma unroll
            for (int j = 0; j < 4; ++j)
                acc[4 + f][j] = __builtin_amdgcn_mfma_f32_16x16x32_bf16(
                    av[f], bv[j], acc[4 + f][j], 0, 0, 0);
        __builtin_amdgcn_s_setprio(0);
        if (t < NT - 2) asm volatile("s_waitcnt vmcnt(4)" ::: "memory");
        else            asm volatile("s_waitcnt vmcnt(0)" ::: "memory");
        asm volatile("s_barrier" ::: "memory");

        if (MIDRELU && t == nt1 - 1) {
#pragma unroll
            for (int j = 0; j < 4; ++j) {
                const float bb = bias1[n0 + wn * 64 + j * 16 + lr];
#pragma unroll
                for (int i = 0; i < 8; ++i)
#pragma unroll
                    for (int r = 0; r < 4; ++r)
                        acc[i][j][r] = fmaxf(acc[i][j][r] + bb, 0.f);
            }
        }
    }

    // ---- epilogue (C/D layout: col=lane&15, row=(lane>>4)*4+reg) ----
    const int cb = n0 + wn * 64 + lr;
    const int rb = m0 + wm * 128 + kq * 4;
#pragma unroll
    for (int j = 0; j < 4; ++j) {
        const int col = cb + j * 16;
        const float bv2 = bias2[col];
#pragma unroll
        for (int i = 0; i < 8; ++i)
#pragma unroll
            for (int r = 0; r < 4; ++r) {
                float v = acc[i][j][r] + bv2;
                if (ENDRELU) v = fmaxf(v, 0.f);
                C[(size_t)(rb + i * 16 + r) * ldc + col] = v;
            }
    }
}

// ---------------------------------------------------------------------------
// Split-K bf16 MFMA GEMM: P[z][M,N] += A[M,kbeg:kend] * Bt[N,kbeg:kend]^T
// 128x128 tile, BK=32, 256 threads; z = blockIdx.z selects K-slice of KS.
// f32 partials, no bias/activation (applied by k_redux).
// ---------------------------------------------------------------------------
__global__ __launch_bounds__(256, 2)
void gemm_splitk(const u16* __restrict__ A, const u16* __restrict__ Bt,
                 float* __restrict__ P, int K, int KS, int N, int MN)
{
    __shared__ u16 sA[128 * 32];
    __shared__ u16 sB[128 * 32];
    const int tid = threadIdx.x;
    const int w = tid >> 6, l = tid & 63;
    const int m0 = blockIdx.y * 128, n0 = blockIdx.x * 128;
    const int wr = (w >> 1) * 64, wc = (w & 1) * 64;

    const int e0 = w * 512 + l * 8;
    const int r0 = e0 >> 5, c0 = e0 & 31;
    const int r1 = r0 + 64;

    const u16* gA0 = A + (size_t)(m0 + r0) * K + c0;
    const u16* gA1 = A + (size_t)(m0 + r1) * K + c0;
    const u16* gB0 = Bt + (size_t)(n0 + r0) * K + c0;
    const u16* gB1 = Bt + (size_t)(n0 + r1) * K + c0;
    u16* lA0 = sA + w * 512;
    u16* lA1 = sA + 2048 + w * 512;
    u16* lB0 = sB + w * 512;
    u16* lB1 = sB + 2048 + w * 512;

    f32x4 acc[4][4] = {};
    const int lr = l & 15, lk = (l >> 4) * 8;
    const int kbeg = blockIdx.z * KS, kend = kbeg + KS;

    for (int k0 = kbeg; k0 < kend; k0 += 32) {
        __syncthreads();
        GLOAD16(gA0 + k0, lA0);
        GLOAD16(gA1 + k0, lA1);
        GLOAD16(gB0 + k0, lB0);
        GLOAD16(gB1 + k0, lB1);
        __syncthreads();

        bf16x8 av[4], bv[4];
#pragma unroll
        for (int f = 0; f < 4; ++f) {
            av[f] = *(const bf16x8*)&sA[(wr + f * 16 + lr) * 32 + lk];
            bv[f] = *(const bf16x8*)&sB[(wc + f * 16 + lr) * 32 + lk];
        }
#pragma unroll
        for (int i = 0; i < 4; ++i)
#pragma unroll
            for (int j = 0; j < 4; ++j)
                acc[i][j] = __builtin_amdgcn_mfma_f32_16x16x32_bf16(
                    av[i], bv[j], acc[i][j], 0, 0, 0);
    }

    float* out = P + (size_t)blockIdx.z * MN;
    const int cb = n0 + wc + lr;
    const int rb = m0 + wr + (l >> 4) * 4;
#pragma unroll
    for (int j = 0; j < 4; ++j) {
        const int c = cb + j * 16;
#pragma unroll
        for (int i = 0; i < 4; ++i)
#pragma unroll
            for (int r = 0; r < 4; ++r)
                out[(size_t)(rb + i * 16 + r) * N + c] = acc[i][j][r];
    }
}

// reduce 4 split-K partials + bias (+relu), store f32 or bf16 with dst stride
template<int RELU, int OUTB>
__global__ void k_redux(const float* __restrict__ P, int MN,
                        const float* __restrict__ bias, void* __restrict__ dst,
                        int ldc, int logN)
{
    const int i4 = (blockIdx.x * 256 + threadIdx.x) * 4;
    float4 s = *(const float4*)(P + i4);
    const float4 v1 = *(const float4*)(P + (size_t)MN + i4);
    const float4 v2 = *(const float4*)(P + (size_t)2 * MN + i4);
    const float4 v3 = *(const float4*)(P + (size_t)3 * MN + i4);
    s.x += v1.x + v2.x + v3.x;
    s.y += v1.y + v2.y + v3.y;
    s.z += v1.z + v2.z + v3.z;
    s.w += v1.w + v2.w + v3.w;
    const int row = i4 >> logN, col = i4 & ((1 << logN) - 1);
    const float4 bb = *(const float4*)(bias + col);
    s.x += bb.x; s.y += bb.y; s.z += bb.z; s.w += bb.w;
    if (RELU) {
        s.x = fmaxf(s.x, 0.f); s.y = fmaxf(s.y, 0.f);
        s.z = fmaxf(s.z, 0.f); s.w = fmaxf(s.w, 0.f);
    }
    if (OUTB) {
        ushort4 o;
        o.x = f2b(s.x); o.y = f2b(s.y); o.z = f2b(s.z); o.w = f2b(s.w);
        *(ushort4*)((u16*)dst + (size_t)row * ldc + col) = o;
    } else {
        *(float4*)((float*)dst + (size_t)row * ldc + col) = s;
    }
}

// ---------------------------------------------------------------------------
// transpose + f32->bf16: Wt[n*K + k] = bf16(W[k*N + n]); K,N multiples of 64
// ---------------------------------------------------------------------------
__global__ void k_transpose(const float* __restrict__ W, u16* __restrict__ Wt,
                            int K, int N)
{
    __shared__ float tile[64][65];
    const int k0 = blockIdx.y * 64, n0 = blockIdx.x * 64;
    const int tr = threadIdx.x >> 6, tc = threadIdx.x & 63;
    for (int rr = tr; rr < 64; rr += 4)
        tile[rr][tc] = W[(size_t)(k0 + rr) * N + n0 + tc];
    __syncthreads();
    for (int rr = tr; rr < 64; rr += 4)
        Wt[(size_t)(n0 + rr) * K + k0 + tc] = f2b(tile[tc][rr]);
}

// f32 -> bf16 elementwise (n multiple of 4)
__global__ void k_f2b4(const float4* __restrict__ in, ushort4* __restrict__ out,
                       int n4)
{
    int i = blockIdx.x * 256 + threadIdx.x;
    const int stride = gridDim.x * 256;
    for (; i < n4; i += stride) {
        float4 v = in[i];
        ushort4 o;
        o.x = f2b(v.x); o.y = f2b(v.y); o.z = f2b(v.z); o.w = f2b(v.w);
        out[i] = o;
    }
}

// softmax(logits) @ emb_dist -> cat1 cols [INCH, INCH+768)
__global__ void k_softmax_embed(const float* __restrict__ logits,
                                const float* __restrict__ embd,
                                u16* __restrict__ cat1)
{
    const int i = blockIdx.x;
    const int t = threadIdx.x;     // 256
    __shared__ float red[256];
    __shared__ float pr[NCLS];
    float v = (t < NCLS) ? logits[i * NCLS + t] : -3.4e38f;
    red[t] = v; __syncthreads();
    for (int s = 128; s > 0; s >>= 1) {
        if (t < s) red[t] = fmaxf(red[t], red[t + s]);
        __syncthreads();
    }
    const float mx = red[0]; __syncthreads();
    float e = (t < NCLS) ? expf(v - mx) : 0.f;
    red[t] = e; __syncthreads();
    for (int s = 128; s > 0; s >>= 1) {
        if (t < s) red[t] += red[t + s];
        __syncthreads();
    }
    const float inv = 1.f / red[0];
    if (t < NCLS) pr[t] = e * inv;
    __syncthreads();
    for (int j = t; j < EMB_; j += 256) {
        float s = 0.f;
        for (int k = 0; k < NCLS; ++k) s += pr[k] * embd[k * EMB_ + j];
        cat1[(size_t)i * 4992 + INCH + j] = f2b(s);
    }
}

// pos MLP: fc1 + BN + fc2 + relu -> cat1 cols [INCH+768, INCH+768+128)
__global__ void k_pos(const float* __restrict__ pos9, const float* __restrict__ w1,
                      const float* __restrict__ b1, const float* __restrict__ g,
                      const float* __restrict__ bb, const float* __restrict__ mu,
                      const float* __restrict__ var, const float* __restrict__ w2,
                      const float* __restrict__ b2, u16* __restrict__ cat1)
{
    const int i = blockIdx.x, t = threadIdx.x;   // 128
    __shared__ float pi[9];
    __shared__ float h[32];
    if (t < 9) pi[t] = pos9[i * 9 + t];
    __syncthreads();
    if (t < 32) {
        float s = b1[t];
        for (int k = 0; k < 9; ++k) s += pi[k] * w1[k * 32 + t];
        h[t] = (s - mu[t]) * rsqrtf(var[t] + 1e-5f) * g[t] + bb[t];
    }
    __syncthreads();
    float s = b2[t];
    for (int k = 0; k < 32; ++k) s += h[k] * w2[k * GEO_ + t];
    cat1[(size_t)i * 4992 + INCH + EMB_ + t] = f2b(fmaxf(s, 0.f));
}

// pack roi -> cat1[0:4096] and aaug[768:4864]; emb_label gather -> aaug[0:768]
__global__ void k_pack(const float* __restrict__ roi, const float* __restrict__ embl,
                       const int* __restrict__ labels, u16* __restrict__ cat1,
                       u16* __restrict__ aaug)
{
    const int i = blockIdx.x, t = threadIdx.x;   // 256
    const float* r = roi + (size_t)i * INCH;
    u16* c1 = cat1 + (size_t)i * 4992;
    u16* aa = aaug + (size_t)i * 5376;
    for (int c = t; c < INCH; c += 256) {
        u16 b = f2b(r[c]);
        c1[c] = b;
        aa[EMB_ + c] = b;
    }
    const float* el = embl + (size_t)labels[i] * EMB_;
    for (int c = t; c < EMB_; c += 256) aa[c] = f2b(el[c]);
}

// geo(32) from boxes + spt1 (K=32) + relu -> bf16 [8192,512]
__global__ void k_geo_spt1(const float* __restrict__ boxes, const int* __restrict__ ridx,
                           const float* __restrict__ w1, const float* __restrict__ b1,
                           u16* __restrict__ out)
{
    const int p = blockIdx.x;        // 0..8191
    const int t = threadIdx.x;       // 256
    const int b = p >> 9;
    __shared__ float geo[32];
    if (t == 0) {
        const int i0 = ridx[p * 2 + 0];
        const int i1 = ridx[p * 2 + 1];
        const float* x = boxes + (size_t)(b * O_ + i0) * 4;
        const float* y = boxes + (size_t)(b * O_ + i1) * 4;
        float a0 = x[0], a1 = x[1], a2 = x[2], a3 = x[3];
        float c0 = y[0], c1 = y[1], c2 = y[2], c3 = y[3];
        geo[0] = a0; geo[1] = a1; geo[2] = a2; geo[3] = a3;
        geo[4] = (a0 + a2) * 0.5f; geo[5] = (a1 + a3) * 0.5f;
        geo[6] = a2 - a0; geo[7] = a3 - a1;
        geo[8] = c0; geo[9] = c1; geo[10] = c2; geo[11] = c3;
        geo[12] = (c0 + c2) * 0.5f; geo[13] = (c1 + c3) * 0.5f;
        geo[14] = c2 - c0; geo[15] = c3 - c1;
        float u0 = fminf(a0, c0), u1 = fminf(a1, c1);
        float u2 = fmaxf(a2, c2), u3 = fmaxf(a3, c3);
        geo[16] = u0; geo[17] = u1; geo[18] = u2; geo[19] = u3;
        geo[20] = (u0 + u2) * 0.5f; geo[21] = (u1 + u3) * 0.5f;
        geo[22] = u2 - u0; geo[23] = u3 - u1;
        float q0 = fmaxf(a0, c0), q1 = fmaxf(a1, c1);
        float q2 = fminf(a2, c2), q3 = fminf(a3, c3);
        if (q0 <= q2 && q1 <= q3) {
            geo[24] = q0; geo[25] = q1; geo[26] = q2; geo[27] = q3;
            geo[28] = (q0 + q2) * 0.5f; geo[29] = (q1 + q3) * 0.5f;
            geo[30] = q2 - q0; geo[31] = q3 - q1;
        } else {
            for (int k = 24; k < 32; ++k) geo[k] = 0.f;
        }
    }
    __syncthreads();
    for (int j = t; j < HID_; j += 256) {
        float s = b1[j];
#pragma unroll
        for (int k = 0; k < 32; ++k) s += geo[k] * w1[k * HID_ + j];
        out[(size_t)p * HID_ + j] = f2b(fmaxf(s, 0.f));
    }
}

// pair gather from fused (bf16) * spt (f32) -> bf16 [8192,1024]
__global__ void k_pairmul(const u16* __restrict__ fused, const float* __restrict__ spt,
                          const int* __restrict__ ridx, u16* __restrict__ apair)
{
    const int idx = blockIdx.x * 256 + threadIdx.x;   // exactly 8192*1024
    const int p = idx >> 10, c = idx & 1023;
    const int b = p >> 9;
    const int part = c >> 9;
    const int ii = ridx[p * 2 + part];
    const float fv = b2f(fused[(size_t)(b * O_ + ii) * 1024 + c]);
    apair[idx] = f2b(fv * spt[idx]);
}

// ---------------------------------------------------------------------------
extern "C" void kernel_launch(void* const* d_in, const int* in_sizes, int n_in,
                              void* d_out, int out_size, void* d_ws, size_t ws_size,
                              hipStream_t stream)
{
    (void)in_sizes; (void)n_in; (void)out_size; (void)ws_size;
    const float* roi     = (const float*)d_in[0];
    const float* unionf  = (const float*)d_in[1];
    const float* logits  = (const float*)d_in[2];
    const float* pos9    = (const float*)d_in[3];
    const float* boxes   = (const float*)d_in[4];
    const int*   labels  = (const int*)d_in[5];
    const int*   relidx  = (const int*)d_in[6];
    const float* embd    = (const float*)d_in[7];
    const float* embl    = (const float*)d_in[8];
    const float* relup_w = (const float*)d_in[9];
    const float* relup_b = (const float*)d_in[10];
    const float* updim_w = (const float*)d_in[11];
    const float* updim_b = (const float*)d_in[12];
    const float* fc1w    = (const float*)d_in[13];
    const float* fc1b    = (const float*)d_in[14];
    const float* bng     = (const float*)d_in[15];
    const float* bnb     = (const float*)d_in[16];
    const float* bnm     = (const float*)d_in[17];
    const float* bnv     = (const float*)d_in[18];
    const float* fc2w    = (const float*)d_in[19];
    const float* fc2b    = (const float*)d_in[20];
    const float* spt1w   = (const float*)d_in[21];
    const float* spt1b   = (const float*)d_in[22];
    const float* spt2w   = (const float*)d_in[23];
    const float* spt2b   = (const float*)d_in[24];
    const float* finw    = (const float*)d_in[25];
    const float* finb    = (const float*)d_in[26];
    const float* objhw   = (const float*)d_in[27];
    const float* objhb   = (const float*)d_in[28];
    const float* augw    = (const float*)d_in[29];
    const float* augb    = (const float*)d_in[30];

    char* wp = (char*)d_ws;
    auto take = [&](size_t bytes) {
        char* r = wp; wp += (bytes + 255) & ~(size_t)255; return r;
    };
    u16* wtObj   = (u16*)take((size_t)512  * 4992 * 2);
    u16* wtUpd   = (u16*)take((size_t)1024 * 5376 * 2);
    u16* wtSpt2  = (u16*)take((size_t)1024 * 512  * 2);
    u16* wtFin   = (u16*)take((size_t)2048 * 1024 * 2);
    u16* wtRelup = (u16*)take((size_t)2048 * 4096 * 2);
    u16* wtAug   = (u16*)take((size_t)2048 * 5376 * 2);
    u16* aCat1   = (u16*)take((size_t)1280 * 4992 * 2);
    u16* aAug    = (u16*)take((size_t)1280 * 5376 * 2);
    u16* aUnion  = (u16*)take((size_t)8192 * 4096 * 2);
    u16* aSpt1   = (u16*)take((size_t)8192 * 512  * 2);
    u16* fusedB  = (u16*)take((size_t)1280 * 1024 * 2);
    u16* aPair   = (u16*)take((size_t)8192 * 1024 * 2);
    float* sptF  = (float*)take((size_t)8192 * 1024 * 4);
    // split-K partial buffer: aliases (aPair + sptF) = 50.3MB >= 42MB needed;
    // dead until after the three split-K GEMMs complete.
    float* Pbuf  = (float*)aPair;

    float* outAug = (float*)d_out;                          // [1280,2048]
    float* outRel = (float*)d_out + (size_t)1280 * 2048;    // [8192,2048]

    // weights -> bf16 transposed (N x K)
    k_transpose<<<dim3(512 / 64, 4992 / 64), 256, 0, stream>>>(objhw,  wtObj,   4992, 512);
    k_transpose<<<dim3(1024 / 64, 5376 / 64), 256, 0, stream>>>(updim_w, wtUpd,  5376, 1024);
    k_transpose<<<dim3(1024 / 64, 512 / 64), 256, 0, stream>>>(spt2w,  wtSpt2,  512, 1024);
    k_transpose<<<dim3(2048 / 64, 1024 / 64), 256, 0, stream>>>(finw,   wtFin,   1024, 2048);
    k_transpose<<<dim3(2048 / 64, 4096 / 64), 256, 0, stream>>>(relup_w, wtRelup, 4096, 2048);
    k_transpose<<<dim3(2048 / 64, 5376 / 64), 256, 0, stream>>>(augw,   wtAug,   5376, 2048);

    // activations prep
    k_f2b4<<<2048, 256, 0, stream>>>((const float4*)unionf, (ushort4*)aUnion,
                                     (8192 * 4096) / 4);
    k_softmax_embed<<<1280, 256, 0, stream>>>(logits, embd, aCat1);
    k_pos<<<1280, 128, 0, stream>>>(pos9, fc1w, fc1b, bng, bnb, bnm, bnv, fc2w, fc2b, aCat1);
    k_pack<<<1280, 256, 0, stream>>>(roi, embl, labels, aCat1, aAug);

    // aug_hid = cat1 @ objhid  (split-K 4, partials f32, reduce -> bf16 cols of aAug)
    gemm_splitk<<<dim3(4, 10, 4), 256, 0, stream>>>(aCat1, wtObj, Pbuf, 4992, 1248,
                                                    512, 1280 * 512);
    k_redux<0, 1><<<640, 256, 0, stream>>>(Pbuf, 1280 * 512, objhb,
                                           (void*)(aAug + 4864), 5376, 9);
    // fused = aAug @ updim  (split-K 4 -> bf16 fusedB)
    gemm_splitk<<<dim3(8, 10, 4), 256, 0, stream>>>(aAug, wtUpd, Pbuf, 5376, 1344,
                                                    1024, 1280 * 1024);
    k_redux<0, 1><<<1280, 256, 0, stream>>>(Pbuf, 1280 * 1024, updim_b,
                                            (void*)fusedB, 1024, 10);
    // augment_out = relu(aAug @ aug_w)  (split-K 4 -> f32 outAug)
    gemm_splitk<<<dim3(16, 10, 4), 256, 0, stream>>>(aAug, wtAug, Pbuf, 5376, 1344,
                                                     2048, 1280 * 2048);
    k_redux<1, 0><<<2560, 256, 0, stream>>>(Pbuf, 1280 * 2048, augb,
                                            (void*)outAug, 2048, 11);

    // geo + spt1
    k_geo_spt1<<<8192, 256, 0, stream>>>(boxes, relidx, spt1w, spt1b, aSpt1);
    // spt = relu(spt1out @ spt2 + b) (f32) via pipelined 256^2 kernel
    gemm256<0, 1><<<dim3(128), 512, 0, stream>>>(
        aSpt1, 512, wtSpt2, 512, 16,
        aSpt1, 512, wtSpt2, 512, 0,
        spt2b, spt2b, sptF, 1024, 4);
    // pair_feat = gather(fused) * spt (bf16)
    k_pairmul<<<(8192 * 1024) / 256, 256, 0, stream>>>(fusedB, sptF, relidx, aPair);

    // rel_features = relu(pair@fin + finb) + union@relup + relup_b  (fused)
    gemm256<1, 0><<<dim3(256), 512, 0, stream>>>(
        aPair, 1024, wtFin, 1024, 32,
        aUnion, 4096, wtRelup, 4096, 128,
        finb, relup_b, outRel, 2048, 8);
}

// Round 4
// 539.360 us; speedup vs baseline: 1.5160x; 1.0116x over previous
//
#include <hip/hip_runtime.h>
#include <hip/hip_bf16.h>

#define B_    16
#define O_    80
#define R_    512
#define INCH  4096
#define NCLS  151
#define EMB_  768
#define HID_  512
#define POOL_ 2048
#define GEO_  128

typedef unsigned short u16;
typedef __attribute__((ext_vector_type(4))) float  f32x4;
typedef __attribute__((ext_vector_type(8))) __bf16 bf16x8;

typedef const __attribute__((address_space(1))) void* as1_t;
typedef __attribute__((address_space(3))) void*       as3_t;
#define GLOAD16(g, l) __builtin_amdgcn_global_load_lds((as1_t)(g), (as3_t)(l), 16, 0, 0)

__device__ __forceinline__ u16 f2b(float f) {
    unsigned u = __float_as_uint(f);
    u += 0x7FFFu + ((u >> 16) & 1u);        // RNE
    return (u16)(u >> 16);
}
__device__ __forceinline__ float b2f(u16 b) {
    return __uint_as_float(((unsigned)b) << 16);
}

// ===========================================================================
// 256x256-tile deep-pipelined bf16 GEMM. BK=64, 4 phases/K-tile, 512 thr
// (8 waves 2Mx4N), LDS 2 x 64KB (1 K-tile per buffer, tile t in buf[t&1]).
//
// Buffer layout (u16 elems): A[ks][128 phys rows][8 slots x 8elems] at
// ks*8192; B same at 16384+ks*8192. Logical A row m (256), k in [0,64):
// ks=k>>5, p=m&127, s_log=(m>>7)*4+((k&31)>>3), s_phys=s_log^(p&7)  ->
// conflict-free ds_read_b128 (proven 0 conflicts in this layout family).
// global_load_lds writes linearly; source address is pre-swizzled (m173).
//
// 8 regions/tile of 8KB = 1 gload x 512thr each:
//   r0=A(ks0,mq0) r1=A(ks0,mq1) r2=A(ks1,mq0) r3=A(ks1,mq1)
//   r4=B(ks0,h0)  r5=B(ks0,h1)  r6=B(ks1,h0)  r7=B(ks1,h1)
// Phase (ks,mq) reads A(ks,mq) + (mq==0: B(ks,*), reg-cached for mq==1).
// Region-ordered staging (issue strictly after the freeing phase's barrier):
//   ph0 of iter u: stage r3,r7 of tile u+1 (freed: read in iter u-1 ph3/ph2)
//   ph1: r0,r4 of tile u+2   (freed by ph0)
//   ph2: r5,r1 of tile u+2   (freed by ph0/ph1)
//   ph3: r2,r6 of tile u+2   (freed by ph2)
// vmcnt(6) once per tile (end ph3): keeps the 6 newest regions in flight,
// each >=7 phases from first read (~1500cy > HBM ~900cy). Tail: vmcnt(0)
// on last two tiles. MIDRELU after tile nt1-1: acc = relu(acc + bias1).
// ===========================================================================
template<int MIDRELU, int ENDRELU>
__global__ __launch_bounds__(512, 2)
void gemm256(const u16* __restrict__ A1i, int lda1, const u16* __restrict__ B1i,
             int ldb1, int nt1,
             const u16* __restrict__ A2i, int lda2, const u16* __restrict__ B2i,
             int ldb2, int nt2,
             const float* __restrict__ bias1, const float* __restrict__ bias2,
             float* __restrict__ C, int ldc, int NBN)
{
    __shared__ u16 lds[2][32768];           // 2 x (A 16384 + B 16384) elems

    const int tid = threadIdx.x;
    const int w = tid >> 6, l = tid & 63;
    const int wm = w >> 2, wn = w & 3;
    const int NT = nt1 + nt2;               // K-tiles of 64

    // XCD-aware block swizzle (gridDim.x % 8 == 0 for all our launches)
    const int nwg = gridDim.x;
    const int cpx = nwg >> 3;
    const int wg  = (blockIdx.x & 7) * cpx + (blockIdx.x >> 3);
    const int mb = wg / NBN, nb = wg % NBN;
    const int m0 = mb * 256, n0 = nb * 256;

    // staging constants (pre-swizzled global source, linear LDS dest)
    const int slA  = (tid & 7) ^ ((tid >> 3) & 7);   // s_log for this thread
    const int mloc = ((slA >> 2) << 7) + (tid >> 3); // logical row (sub=0)
    const int kloc = (slA & 3) << 3;                 // k offset within kstep
    const int wo   = w << 9;                         // wave-uniform LDS base

    auto stage = [&](int st, int reg8, u16* buf) {
        if (st >= NT) return;
        const int isA = (reg8 < 4) ? 1 : 0;
        const int ks  = (reg8 >> 1) & 1, sub = reg8 & 1;
        const u16* base; int ld, stl;
        if (st < nt1) { base = isA ? A1i : B1i; ld = isA ? lda1 : ldb1; stl = st; }
        else          { base = isA ? A2i : B2i; ld = isA ? lda2 : ldb2; stl = st - nt1; }
        const int x0 = isA ? m0 : n0;
        const u16* src = base + (size_t)(x0 + mloc + (sub << 6)) * ld
                       + stl * 64 + ks * 32 + kloc;
        u16* dst = buf + (isA ? 0 : 16384) + (ks << 13) + (sub << 12) + wo;
        GLOAD16(src, dst);
    };

    // fragment read offsets (swizzled)
    const int lr = l & 15, kq = l >> 4, lr7 = l & 7;
    const int aob = lr * 64 + (((wm << 2) | kq) ^ lr7) * 8;   // +ks*8192+mq*4096+f*1024
    const int bob = 16384 + ((wn & 1) << 12) + lr * 64
                  + ((((wn >> 1) << 2) | kq) ^ lr7) * 8;      // +ks*8192+j*1024

    f32x4 acc[8][4] = {};

    u16* const b0 = &lds[0][0];
    u16* const b1 = &lds[1][0];

    // ---- prologue: tile0 fully -> buf0; tile1 regions 0,1,2,4,5,6 -> buf1 ----
#pragma unroll
    for (int r8 = 0; r8 < 8; ++r8) stage(0, r8, b0);
    stage(1, 0, b1); stage(1, 1, b1); stage(1, 2, b1);
    stage(1, 4, b1); stage(1, 5, b1); stage(1, 6, b1);
    asm volatile("s_waitcnt vmcnt(0)" ::: "memory");
    asm volatile("s_barrier" ::: "memory");

    for (int u = 0; u < NT; ++u) {
        u16* const bufc = (u & 1) ? b1 : b0;
        u16* const bufn = (u & 1) ? b0 : b1;
        bf16x8 av[4], bv[4];

        // ============ phase 0: ks=0, mq=0 ============
#pragma unroll
        for (int j = 0; j < 4; ++j)
            bv[j] = *(const bf16x8*)(bufc + bob + j * 1024);
#pragma unroll
        for (int f = 0; f < 4; ++f)
            av[f] = *(const bf16x8*)(bufc + aob + f * 1024);
        stage(u + 1, 3, bufn); stage(u + 1, 7, bufn);
        asm volatile("s_barrier" ::: "memory");
        __builtin_amdgcn_sched_barrier(0);
        __builtin_amdgcn_s_setprio(1);
#pragma unroll
        for (int f = 0; f < 4; ++f)
#pragma unroll
            for (int j = 0; j < 4; ++j)
                acc[f][j] = __builtin_amdgcn_mfma_f32_16x16x32_bf16(
                    av[f], bv[j], acc[f][j], 0, 0, 0);
        __builtin_amdgcn_s_setprio(0);
        asm volatile("s_barrier" ::: "memory");

        // ============ phase 1: ks=0, mq=1 ============
#pragma unroll
        for (int f = 0; f < 4; ++f)
            av[f] = *(const bf16x8*)(bufc + aob + 4096 + f * 1024);
        stage(u + 2, 0, bufc); stage(u + 2, 4, bufc);
        asm volatile("s_barrier" ::: "memory");
        __builtin_amdgcn_sched_barrier(0);
        __builtin_amdgcn_s_setprio(1);
#pragma unroll
        for (int f = 0; f < 4; ++f)
#pragma unroll
            for (int j = 0; j < 4; ++j)
                acc[4 + f][j] = __builtin_amdgcn_mfma_f32_16x16x32_bf16(
                    av[f], bv[j], acc[4 + f][j], 0, 0, 0);
        __builtin_amdgcn_s_setprio(0);
        asm volatile("s_barrier" ::: "memory");

        // ============ phase 2: ks=1, mq=0 ============
#pragma unroll
        for (int j = 0; j < 4; ++j)
            bv[j] = *(const bf16x8*)(bufc + 8192 + bob + j * 1024);
#pragma unroll
        for (int f = 0; f < 4; ++f)
            av[f] = *(const bf16x8*)(bufc + 8192 + aob + f * 1024);
        stage(u + 2, 5, bufc); stage(u + 2, 1, bufc);
        asm volatile("s_barrier" ::: "memory");
        __builtin_amdgcn_sched_barrier(0);
        __builtin_amdgcn_s_setprio(1);
#pragma unroll
        for (int f = 0; f < 4; ++f)
#pragma unroll
            for (int j = 0; j < 4; ++j)
                acc[f][j] = __builtin_amdgcn_mfma_f32_16x16x32_bf16(
                    av[f], bv[j], acc[f][j], 0, 0, 0);
        __builtin_amdgcn_s_setprio(0);
        asm volatile("s_barrier" ::: "memory");

        // ============ phase 3: ks=1, mq=1 ============
#pragma unroll
        for (int f = 0; f < 4; ++f)
            av[f] = *(const bf16x8*)(bufc + 8192 + aob + 4096 + f * 1024);
        stage(u + 2, 2, bufc); stage(u + 2, 6, bufc);
        asm volatile("s_barrier" ::: "memory");
        __builtin_amdgcn_sched_barrier(0);
        __builtin_amdgcn_s_setprio(1);
#pragma unroll
        for (int f = 0; f < 4; ++f)
#pragma unroll
            for (int j = 0; j < 4; ++j)
                acc[4 + f][j] = __builtin_amdgcn_mfma_f32_16x16x32_bf16(
                    av[f], bv[j], acc[4 + f][j], 0, 0, 0);
        __builtin_amdgcn_s_setprio(0);
        if (u < NT - 2) asm volatile("s_waitcnt vmcnt(6)" ::: "memory");
        else            asm volatile("s_waitcnt vmcnt(0)" ::: "memory");
        asm volatile("s_barrier" ::: "memory");

        // segment boundary: acc = relu(acc + bias1)
        if (MIDRELU && u == nt1 - 1) {
#pragma unroll
            for (int j = 0; j < 4; ++j) {
                const float bb = bias1[n0 + wn * 64 + j * 16 + lr];
#pragma unroll
                for (int i = 0; i < 8; ++i)
#pragma unroll
                    for (int r = 0; r < 4; ++r)
                        acc[i][j][r] = fmaxf(acc[i][j][r] + bb, 0.f);
            }
        }
    }

    // ---- epilogue (C/D layout: col=lane&15, row=(lane>>4)*4+reg) ----
    const int cb = n0 + wn * 64 + lr;
    const int rb = m0 + wm * 128 + kq * 4;
#pragma unroll
    for (int j = 0; j < 4; ++j) {
        const int col = cb + j * 16;
        const float bv2 = bias2[col];
#pragma unroll
        for (int i = 0; i < 8; ++i)
#pragma unroll
            for (int r = 0; r < 4; ++r) {
                float v = acc[i][j][r] + bv2;
                if (ENDRELU) v = fmaxf(v, 0.f);
                C[(size_t)(rb + i * 16 + r) * ldc + col] = v;
            }
    }
}

// ---------------------------------------------------------------------------
// Split-K bf16 MFMA GEMM: P[z][M,N] += A[M,kbeg:kend] * Bt[N,kbeg:kend]^T
// 128x128 tile, BK=32, 256 threads; z = blockIdx.z selects K-slice of KS.
// ---------------------------------------------------------------------------
__global__ __launch_bounds__(256, 2)
void gemm_splitk(const u16* __restrict__ A, const u16* __restrict__ Bt,
                 float* __restrict__ P, int K, int KS, int N, int MN)
{
    __shared__ u16 sA[128 * 32];
    __shared__ u16 sB[128 * 32];
    const int tid = threadIdx.x;
    const int w = tid >> 6, l = tid & 63;
    const int m0 = blockIdx.y * 128, n0 = blockIdx.x * 128;
    const int wr = (w >> 1) * 64, wc = (w & 1) * 64;

    const int e0 = w * 512 + l * 8;
    const int r0 = e0 >> 5, c0 = e0 & 31;
    const int r1 = r0 + 64;

    const u16* gA0 = A + (size_t)(m0 + r0) * K + c0;
    const u16* gA1 = A + (size_t)(m0 + r1) * K + c0;
    const u16* gB0 = Bt + (size_t)(n0 + r0) * K + c0;
    const u16* gB1 = Bt + (size_t)(n0 + r1) * K + c0;
    u16* lA0 = sA + w * 512;
    u16* lA1 = sA + 2048 + w * 512;
    u16* lB0 = sB + w * 512;
    u16* lB1 = sB + 2048 + w * 512;

    f32x4 acc[4][4] = {};
    const int lr = l & 15, lk = (l >> 4) * 8;
    const int kbeg = blockIdx.z * KS, kend = kbeg + KS;

    for (int k0 = kbeg; k0 < kend; k0 += 32) {
        __syncthreads();
        GLOAD16(gA0 + k0, lA0);
        GLOAD16(gA1 + k0, lA1);
        GLOAD16(gB0 + k0, lB0);
        GLOAD16(gB1 + k0, lB1);
        __syncthreads();

        bf16x8 av[4], bv[4];
#pragma unroll
        for (int f = 0; f < 4; ++f) {
            av[f] = *(const bf16x8*)&sA[(wr + f * 16 + lr) * 32 + lk];
            bv[f] = *(const bf16x8*)&sB[(wc + f * 16 + lr) * 32 + lk];
        }
#pragma unroll
        for (int i = 0; i < 4; ++i)
#pragma unroll
            for (int j = 0; j < 4; ++j)
                acc[i][j] = __builtin_amdgcn_mfma_f32_16x16x32_bf16(
                    av[i], bv[j], acc[i][j], 0, 0, 0);
    }

    float* out = P + (size_t)blockIdx.z * MN;
    const int cb = n0 + wc + lr;
    const int rb = m0 + wr + (l >> 4) * 4;
#pragma unroll
    for (int j = 0; j < 4; ++j) {
        const int c = cb + j * 16;
#pragma unroll
        for (int i = 0; i < 4; ++i)
#pragma unroll
            for (int r = 0; r < 4; ++r)
                out[(size_t)(rb + i * 16 + r) * N + c] = acc[i][j][r];
    }
}

// reduce 4 split-K partials + bias (+relu), store f32 or bf16 with dst stride
template<int RELU, int OUTB>
__global__ void k_redux(const float* __restrict__ P, int MN,
                        const float* __restrict__ bias, void* __restrict__ dst,
                        int ldc, int logN)
{
    const int i4 = (blockIdx.x * 256 + threadIdx.x) * 4;
    float4 s = *(const float4*)(P + i4);
    const float4 v1 = *(const float4*)(P + (size_t)MN + i4);
    const float4 v2 = *(const float4*)(P + (size_t)2 * MN + i4);
    const float4 v3 = *(const float4*)(P + (size_t)3 * MN + i4);
    s.x += v1.x + v2.x + v3.x;
    s.y += v1.y + v2.y + v3.y;
    s.z += v1.z + v2.z + v3.z;
    s.w += v1.w + v2.w + v3.w;
    const int row = i4 >> logN, col = i4 & ((1 << logN) - 1);
    const float4 bb = *(const float4*)(bias + col);
    s.x += bb.x; s.y += bb.y; s.z += bb.z; s.w += bb.w;
    if (RELU) {
        s.x = fmaxf(s.x, 0.f); s.y = fmaxf(s.y, 0.f);
        s.z = fmaxf(s.z, 0.f); s.w = fmaxf(s.w, 0.f);
    }
    if (OUTB) {
        ushort4 o;
        o.x = f2b(s.x); o.y = f2b(s.y); o.z = f2b(s.z); o.w = f2b(s.w);
        *(ushort4*)((u16*)dst + (size_t)row * ldc + col) = o;
    } else {
        *(float4*)((float*)dst + (size_t)row * ldc + col) = s;
    }
}

// ---------------------------------------------------------------------------
// transpose + f32->bf16: Wt[n*K + k] = bf16(W[k*N + n]); K,N multiples of 64
// ---------------------------------------------------------------------------
__global__ void k_transpose(const float* __restrict__ W, u16* __restrict__ Wt,
                            int K, int N)
{
    __shared__ float tile[64][65];
    const int k0 = blockIdx.y * 64, n0 = blockIdx.x * 64;
    const int tr = threadIdx.x >> 6, tc = threadIdx.x & 63;
    for (int rr = tr; rr < 64; rr += 4)
        tile[rr][tc] = W[(size_t)(k0 + rr) * N + n0 + tc];
    __syncthreads();
    for (int rr = tr; rr < 64; rr += 4)
        Wt[(size_t)(n0 + rr) * K + k0 + tc] = f2b(tile[tc][rr]);
}

// f32 -> bf16 elementwise (n multiple of 4)
__global__ void k_f2b4(const float4* __restrict__ in, ushort4* __restrict__ out,
                       int n4)
{
    int i = blockIdx.x * 256 + threadIdx.x;
    const int stride = gridDim.x * 256;
    for (; i < n4; i += stride) {
        float4 v = in[i];
        ushort4 o;
        o.x = f2b(v.x); o.y = f2b(v.y); o.z = f2b(v.z); o.w = f2b(v.w);
        out[i] = o;
    }
}

// softmax(logits) @ emb_dist -> cat1 cols [INCH, INCH+768)
__global__ void k_softmax_embed(const float* __restrict__ logits,
                                const float* __restrict__ embd,
                                u16* __restrict__ cat1)
{
    const int i = blockIdx.x;
    const int t = threadIdx.x;     // 256
    __shared__ float red[256];
    __shared__ float pr[NCLS];
    float v = (t < NCLS) ? logits[i * NCLS + t] : -3.4e38f;
    red[t] = v; __syncthreads();
    for (int s = 128; s > 0; s >>= 1) {
        if (t < s) red[t] = fmaxf(red[t], red[t + s]);
        __syncthreads();
    }
    const float mx = red[0]; __syncthreads();
    float e = (t < NCLS) ? expf(v - mx) : 0.f;
    red[t] = e; __syncthreads();
    for (int s = 128; s > 0; s >>= 1) {
        if (t < s) red[t] += red[t + s];
        __syncthreads();
    }
    const float inv = 1.f / red[0];
    if (t < NCLS) pr[t] = e * inv;
    __syncthreads();
    for (int j = t; j < EMB_; j += 256) {
        float s = 0.f;
        for (int k = 0; k < NCLS; ++k) s += pr[k] * embd[k * EMB_ + j];
        cat1[(size_t)i * 4992 + INCH + j] = f2b(s);
    }
}

// pos MLP: fc1 + BN + fc2 + relu -> cat1 cols [INCH+768, INCH+768+128)
__global__ void k_pos(const float* __restrict__ pos9, const float* __restrict__ w1,
                      const float* __restrict__ b1, const float* __restrict__ g,
                      const float* __restrict__ bb, const float* __restrict__ mu,
                      const float* __restrict__ var, const float* __restrict__ w2,
                      const float* __restrict__ b2, u16* __restrict__ cat1)
{
    const int i = blockIdx.x, t = threadIdx.x;   // 128
    __shared__ float pi[9];
    __shared__ float h[32];
    if (t < 9) pi[t] = pos9[i * 9 + t];
    __syncthreads();
    if (t < 32) {
        float s = b1[t];
        for (int k = 0; k < 9; ++k) s += pi[k] * w1[k * 32 + t];
        h[t] = (s - mu[t]) * rsqrtf(var[t] + 1e-5f) * g[t] + bb[t];
    }
    __syncthreads();
    float s = b2[t];
    for (int k = 0; k < 32; ++k) s += h[k] * w2[k * GEO_ + t];
    cat1[(size_t)i * 4992 + INCH + EMB_ + t] = f2b(fmaxf(s, 0.f));
}

// pack roi -> cat1[0:4096] and aaug[768:4864]; emb_label gather -> aaug[0:768]
__global__ void k_pack(const float* __restrict__ roi, const float* __restrict__ embl,
                       const int* __restrict__ labels, u16* __restrict__ cat1,
                       u16* __restrict__ aaug)
{
    const int i = blockIdx.x, t = threadIdx.x;   // 256
    const float* r = roi + (size_t)i * INCH;
    u16* c1 = cat1 + (size_t)i * 4992;
    u16* aa = aaug + (size_t)i * 5376;
    for (int c = t; c < INCH; c += 256) {
        u16 b = f2b(r[c]);
        c1[c] = b;
        aa[EMB_ + c] = b;
    }
    const float* el = embl + (size_t)labels[i] * EMB_;
    for (int c = t; c < EMB_; c += 256) aa[c] = f2b(el[c]);
}

// geo(32) from boxes + spt1 (K=32) + relu -> bf16 [8192,512]
__global__ void k_geo_spt1(const float* __restrict__ boxes, const int* __restrict__ ridx,
                           const float* __restrict__ w1, const float* __restrict__ b1,
                           u16* __restrict__ out)
{
    const int p = blockIdx.x;        // 0..8191
    const int t = threadIdx.x;       // 256
    const int b = p >> 9;
    __shared__ float geo[32];
    if (t == 0) {
        const int i0 = ridx[p * 2 + 0];
        const int i1 = ridx[p * 2 + 1];
        const float* x = boxes + (size_t)(b * O_ + i0) * 4;
        const float* y = boxes + (size_t)(b * O_ + i1) * 4;
        float a0 = x[0], a1 = x[1], a2 = x[2], a3 = x[3];
        float c0 = y[0], c1 = y[1], c2 = y[2], c3 = y[3];
        geo[0] = a0; geo[1] = a1; geo[2] = a2; geo[3] = a3;
        geo[4] = (a0 + a2) * 0.5f; geo[5] = (a1 + a3) * 0.5f;
        geo[6] = a2 - a0; geo[7] = a3 - a1;
        geo[8] = c0; geo[9] = c1; geo[10] = c2; geo[11] = c3;
        geo[12] = (c0 + c2) * 0.5f; geo[13] = (c1 + c3) * 0.5f;
        geo[14] = c2 - c0; geo[15] = c3 - c1;
        float u0 = fminf(a0, c0), u1 = fminf(a1, c1);
        float u2 = fmaxf(a2, c2), u3 = fmaxf(a3, c3);
        geo[16] = u0; geo[17] = u1; geo[18] = u2; geo[19] = u3;
        geo[20] = (u0 + u2) * 0.5f; geo[21] = (u1 + u3) * 0.5f;
        geo[22] = u2 - u0; geo[23] = u3 - u1;
        float q0 = fmaxf(a0, c0), q1 = fmaxf(a1, c1);
        float q2 = fminf(a2, c2), q3 = fminf(a3, c3);
        if (q0 <= q2 && q1 <= q3) {
            geo[24] = q0; geo[25] = q1; geo[26] = q2; geo[27] = q3;
            geo[28] = (q0 + q2) * 0.5f; geo[29] = (q1 + q3) * 0.5f;
            geo[30] = q2 - q0; geo[31] = q3 - q1;
        } else {
            for (int k = 24; k < 32; ++k) geo[k] = 0.f;
        }
    }
    __syncthreads();
    for (int j = t; j < HID_; j += 256) {
        float s = b1[j];
#pragma unroll
        for (int k = 0; k < 32; ++k) s += geo[k] * w1[k * HID_ + j];
        out[(size_t)p * HID_ + j] = f2b(fmaxf(s, 0.f));
    }
}

// pair gather from fused (bf16) * spt (f32) -> bf16 [8192,1024]
__global__ void k_pairmul(const u16* __restrict__ fused, const float* __restrict__ spt,
                          const int* __restrict__ ridx, u16* __restrict__ apair)
{
    const int idx = blockIdx.x * 256 + threadIdx.x;   // exactly 8192*1024
    const int p = idx >> 10, c = idx & 1023;
    const int b = p >> 9;
    const int part = c >> 9;
    const int ii = ridx[p * 2 + part];
    const float fv = b2f(fused[(size_t)(b * O_ + ii) * 1024 + c]);
    apair[idx] = f2b(fv * spt[idx]);
}

// ---------------------------------------------------------------------------
extern "C" void kernel_launch(void* const* d_in, const int* in_sizes, int n_in,
                              void* d_out, int out_size, void* d_ws, size_t ws_size,
                              hipStream_t stream)
{
    (void)in_sizes; (void)n_in; (void)out_size; (void)ws_size;
    const float* roi     = (const float*)d_in[0];
    const float* unionf  = (const float*)d_in[1];
    const float* logits  = (const float*)d_in[2];
    const float* pos9    = (const float*)d_in[3];
    const float* boxes   = (const float*)d_in[4];
    const int*   labels  = (const int*)d_in[5];
    const int*   relidx  = (const int*)d_in[6];
    const float* embd    = (const float*)d_in[7];
    const float* embl    = (const float*)d_in[8];
    const float* relup_w = (const float*)d_in[9];
    const float* relup_b = (const float*)d_in[10];
    const float* updim_w = (const float*)d_in[11];
    const float* updim_b = (const float*)d_in[12];
    const float* fc1w    = (const float*)d_in[13];
    const float* fc1b    = (const float*)d_in[14];
    const float* bng     = (const float*)d_in[15];
    const float* bnb     = (const float*)d_in[16];
    const float* bnm     = (const float*)d_in[17];
    const float* bnv     = (const float*)d_in[18];
    const float* fc2w    = (const float*)d_in[19];
    const float* fc2b    = (const float*)d_in[20];
    const float* spt1w   = (const float*)d_in[21];
    const float* spt1b   = (const float*)d_in[22];
    const float* spt2w   = (const float*)d_in[23];
    const float* spt2b   = (const float*)d_in[24];
    const float* finw    = (const float*)d_in[25];
    const float* finb    = (const float*)d_in[26];
    const float* objhw   = (const float*)d_in[27];
    const float* objhb   = (const float*)d_in[28];
    const float* augw    = (const float*)d_in[29];
    const float* augb    = (const float*)d_in[30];

    char* wp = (char*)d_ws;
    auto take = [&](size_t bytes) {
        char* r = wp; wp += (bytes + 255) & ~(size_t)255; return r;
    };
    u16* wtObj   = (u16*)take((size_t)512  * 4992 * 2);
    u16* wtUpd   = (u16*)take((size_t)1024 * 5376 * 2);
    u16* wtSpt2  = (u16*)take((size_t)1024 * 512  * 2);
    u16* wtFin   = (u16*)take((size_t)2048 * 1024 * 2);
    u16* wtRelup = (u16*)take((size_t)2048 * 4096 * 2);
    u16* wtAug   = (u16*)take((size_t)2048 * 5376 * 2);
    u16* aCat1   = (u16*)take((size_t)1280 * 4992 * 2);
    u16* aAug    = (u16*)take((size_t)1280 * 5376 * 2);
    u16* aUnion  = (u16*)take((size_t)8192 * 4096 * 2);
    u16* aSpt1   = (u16*)take((size_t)8192 * 512  * 2);
    u16* fusedB  = (u16*)take((size_t)1280 * 1024 * 2);
    u16* aPair   = (u16*)take((size_t)8192 * 1024 * 2);
    float* sptF  = (float*)take((size_t)8192 * 1024 * 4);
    // split-K partial buffer: aliases (aPair + sptF) = 50.3MB >= 42MB needed;
    // dead until after the three split-K GEMMs complete.
    float* Pbuf  = (float*)aPair;

    float* outAug = (float*)d_out;                          // [1280,2048]
    float* outRel = (float*)d_out + (size_t)1280 * 2048;    // [8192,2048]

    // weights -> bf16 transposed (N x K)
    k_transpose<<<dim3(512 / 64, 4992 / 64), 256, 0, stream>>>(objhw,  wtObj,   4992, 512);
    k_transpose<<<dim3(1024 / 64, 5376 / 64), 256, 0, stream>>>(updim_w, wtUpd,  5376, 1024);
    k_transpose<<<dim3(1024 / 64, 512 / 64), 256, 0, stream>>>(spt2w,  wtSpt2,  512, 1024);
    k_transpose<<<dim3(2048 / 64, 1024 / 64), 256, 0, stream>>>(finw,   wtFin,   1024, 2048);
    k_transpose<<<dim3(2048 / 64, 4096 / 64), 256, 0, stream>>>(relup_w, wtRelup, 4096, 2048);
    k_transpose<<<dim3(2048 / 64, 5376 / 64), 256, 0, stream>>>(augw,   wtAug,   5376, 2048);

    // activations prep
    k_f2b4<<<2048, 256, 0, stream>>>((const float4*)unionf, (ushort4*)aUnion,
                                     (8192 * 4096) / 4);
    k_softmax_embed<<<1280, 256, 0, stream>>>(logits, embd, aCat1);
    k_pos<<<1280, 128, 0, stream>>>(pos9, fc1w, fc1b, bng, bnb, bnm, bnv, fc2w, fc2b, aCat1);
    k_pack<<<1280, 256, 0, stream>>>(roi, embl, labels, aCat1, aAug);

    // aug_hid = cat1 @ objhid  (split-K 4, partials f32, reduce -> bf16 cols of aAug)
    gemm_splitk<<<dim3(4, 10, 4), 256, 0, stream>>>(aCat1, wtObj, Pbuf, 4992, 1248,
                                                    512, 1280 * 512);
    k_redux<0, 1><<<640, 256, 0, stream>>>(Pbuf, 1280 * 512, objhb,
                                           (void*)(aAug + 4864), 5376, 9);
    // fused = aAug @ updim  (split-K 4 -> bf16 fusedB)
    gemm_splitk<<<dim3(8, 10, 4), 256, 0, stream>>>(aAug, wtUpd, Pbuf, 5376, 1344,
                                                    1024, 1280 * 1024);
    k_redux<0, 1><<<1280, 256, 0, stream>>>(Pbuf, 1280 * 1024, updim_b,
                                            (void*)fusedB, 1024, 10);
    // augment_out = relu(aAug @ aug_w)  (split-K 4 -> f32 outAug)
    gemm_splitk<<<dim3(16, 10, 4), 256, 0, stream>>>(aAug, wtAug, Pbuf, 5376, 1344,
                                                     2048, 1280 * 2048);
    k_redux<1, 0><<<2560, 256, 0, stream>>>(Pbuf, 1280 * 2048, augb,
                                            (void*)outAug, 2048, 11);

    // geo + spt1
    k_geo_spt1<<<8192, 256, 0, stream>>>(boxes, relidx, spt1w, spt1b, aSpt1);
    // spt = relu(spt1out @ spt2 + b) (f32), K=512 -> 8 tiles of 64
    gemm256<0, 1><<<dim3(128), 512, 0, stream>>>(
        aSpt1, 512, wtSpt2, 512, 8,
        aSpt1, 512, wtSpt2, 512, 0,
        spt2b, spt2b, sptF, 1024, 4);
    // pair_feat = gather(fused) * spt (bf16)
    k_pairmul<<<(8192 * 1024) / 256, 256, 0, stream>>>(fusedB, sptF, relidx, aPair);

    // rel_features = relu(pair@fin + finb) + union@relup + relup_b  (fused)
    // K1 = 1024 -> 16 tiles; K2 = 4096 -> 64 tiles
    gemm256<1, 0><<<dim3(256), 512, 0, stream>>>(
        aPair, 1024, wtFin, 1024, 16,
        aUnion, 4096, wtRelup, 4096, 64,
        finb, relup_b, outRel, 2048, 8);
}

// Round 5
// 517.696 us; speedup vs baseline: 1.5794x; 1.0418x over previous
//
#include <hip/hip_runtime.h>
#include <hip/hip_bf16.h>

#define B_    16
#define O_    80
#define R_    512
#define INCH  4096
#define NCLS  151
#define EMB_  768
#define HID_  512
#define POOL_ 2048
#define GEO_  128

typedef unsigned short u16;
typedef __attribute__((ext_vector_type(4))) float  f32x4;
typedef __attribute__((ext_vector_type(8))) __bf16 bf16x8;

typedef const __attribute__((address_space(1))) void* as1_t;
typedef __attribute__((address_space(3))) void*       as3_t;
#define GLOAD16(g, l) __builtin_amdgcn_global_load_lds((as1_t)(g), (as3_t)(l), 16, 0, 0)

__device__ __forceinline__ u16 f2b(float f) {
    unsigned u = __float_as_uint(f);
    u += 0x7FFFu + ((u >> 16) & 1u);        // RNE
    return (u16)(u >> 16);
}
__device__ __forceinline__ float b2f(u16 b) {
    return __uint_as_float(((unsigned)b) << 16);
}

// ===========================================================================
// 256x256-tile bf16 GEMM, BK=64, 512 thr (8 waves 2Mx4N), LDS 2x64KB.
// R5: register-level fragment double-buffer — step Xi reads frags for X(i+1)
// while MFMA-ing frags loaded at X(i-1); only 2 barriers + 1 vmcnt per K-tile.
// LDS layout + swizzle identical to R2-R4 (refcheck-proven, 0 conflicts).
// Regions (8KB, 1 gload x 512thr): r0=A(ks0,m0) r1=A(ks0,m1) r2=A(ks1,m0)
// r3=A(ks1,m1) r4,r5=B(ks0) r6,r7=B(ks1).
// Step schedule per iter u (tile u in bufc=lds[u&1], staging tile u+2 there):
//  X0: [alpha barrier] read avB<-r1 | stage r0,r4,r5(u+2) | MFMA(avA,bvA)->acc[0..3]
//  X1: read avA<-r2, bvB<-r6,r7    |                      | MFMA(avB,bvA)->acc[4..7]
//  X2: read avB<-r3                | stage r1,r2,r6,r7    | MFMA(avA,bvB)->acc[0..3]
//  X3: [vmcnt(7); beta barrier] pre-read avA,bvA<-bufn r0,r4,r5 | stage r3 |
//      MFMA(avB,bvB)->acc[4..7]
// vmcnt(7) retires all of tile u+1 (its last region r3 was issued at X3(u-1)),
// keeping the 7 loads issued this iter (X0:3 + X2:4). Every region's re-stage
// is >=1 full step (>=350cy + >=200cy gload landing) after its last read.
// ===========================================================================
template<int MIDRELU, int ENDRELU>
__global__ __launch_bounds__(512, 2)
void gemm256(const u16* __restrict__ A1i, int lda1, const u16* __restrict__ B1i,
             int ldb1, int nt1,
             const u16* __restrict__ A2i, int lda2, const u16* __restrict__ B2i,
             int ldb2, int nt2,
             const float* __restrict__ bias1, const float* __restrict__ bias2,
             float* __restrict__ C, int ldc, int NBN)
{
    __shared__ u16 lds[2][32768];           // 2 x (A 16384 + B 16384) elems

    const int tid = threadIdx.x;
    const int w = tid >> 6, l = tid & 63;
    const int wm = w >> 2, wn = w & 3;
    const int NT = nt1 + nt2;               // K-tiles of 64

    // XCD-aware block swizzle (gridDim.x % 8 == 0 for all our launches)
    const int nwg = gridDim.x;
    const int cpx = nwg >> 3;
    const int wg  = (blockIdx.x & 7) * cpx + (blockIdx.x >> 3);
    const int mb = wg / NBN, nb = wg % NBN;
    const int m0 = mb * 256, n0 = nb * 256;

    // staging constants (pre-swizzled global source, linear LDS dest)
    const int slA  = (tid & 7) ^ ((tid >> 3) & 7);   // s_log for this thread
    const int mloc = ((slA >> 2) << 7) + (tid >> 3); // logical row (sub=0)
    const int kloc = (slA & 3) << 3;                 // k offset within kstep
    const int wo   = w << 9;                         // wave-uniform LDS base

    auto stage = [&](int st, int reg8, u16* buf) {
        if (st >= NT) return;
        const int isA = (reg8 < 4) ? 1 : 0;
        const int ks  = (reg8 >> 1) & 1, sub = reg8 & 1;
        const u16* base; int ld, stl;
        if (st < nt1) { base = isA ? A1i : B1i; ld = isA ? lda1 : ldb1; stl = st; }
        else          { base = isA ? A2i : B2i; ld = isA ? lda2 : ldb2; stl = st - nt1; }
        const int x0 = isA ? m0 : n0;
        const u16* src = base + (size_t)(x0 + mloc + (sub << 6)) * ld
                       + stl * 64 + ks * 32 + kloc;
        u16* dst = buf + (isA ? 0 : 16384) + (ks << 13) + (sub << 12) + wo;
        GLOAD16(src, dst);
    };

    // fragment read offsets (swizzled); A(ks,mq) frag f at
    //   aob + ks*8192 + mq*4096 + f*1024 ; B(ks) frag j at bob + ks*8192 + j*1024
    const int lr = l & 15, kq = l >> 4, lr7 = l & 7;
    const int aob = lr * 64 + (((wm << 2) | kq) ^ lr7) * 8;
    const int bob = 16384 + ((wn & 1) << 12) + lr * 64
                  + ((((wn >> 1) << 2) | kq) ^ lr7) * 8;

    f32x4 acc[8][4] = {};
    bf16x8 avA[4], avB[4], bvA[4], bvB[4];

    u16* const b0 = &lds[0][0];
    u16* const b1 = &lds[1][0];

    // ---- prologue: stage tiles 0 and 1 fully; land tile 0; pre-read X0 frags
#pragma unroll
    for (int r8 = 0; r8 < 8; ++r8) stage(0, r8, b0);
#pragma unroll
    for (int r8 = 0; r8 < 8; ++r8) stage(1, r8, b1);
    asm volatile("s_waitcnt vmcnt(8)" ::: "memory");
    asm volatile("s_barrier" ::: "memory");
#pragma unroll
    for (int f = 0; f < 4; ++f) avA[f] = *(const bf16x8*)(b0 + aob + f * 1024);
#pragma unroll
    for (int j = 0; j < 4; ++j) bvA[j] = *(const bf16x8*)(b0 + bob + j * 1024);

    for (int u = 0; u < NT; ++u) {
        u16* const bufc = (u & 1) ? b1 : b0;
        u16* const bufn = (u & 1) ? b0 : b1;

        // ======== X0: MFMA(ks0,mq0); read avB<-A(ks0,mq1); stage r0,r4,r5 ====
        asm volatile("s_barrier" ::: "memory");          // alpha
#pragma unroll
        for (int f = 0; f < 4; ++f)
            avB[f] = *(const bf16x8*)(bufc + 4096 + aob + f * 1024);
        stage(u + 2, 0, bufc); stage(u + 2, 4, bufc); stage(u + 2, 5, bufc);
        __builtin_amdgcn_s_setprio(1);
#pragma unroll
        for (int f = 0; f < 4; ++f)
#pragma unroll
            for (int j = 0; j < 4; ++j)
                acc[f][j] = __builtin_amdgcn_mfma_f32_16x16x32_bf16(
                    avA[f], bvA[j], acc[f][j], 0, 0, 0);
        __builtin_amdgcn_s_setprio(0);

        // ======== X1: MFMA(ks0,mq1); read avA<-A(ks1,mq0), bvB<-B(ks1) ======
#pragma unroll
        for (int f = 0; f < 4; ++f)
            avA[f] = *(const bf16x8*)(bufc + 8192 + aob + f * 1024);
#pragma unroll
        for (int j = 0; j < 4; ++j)
            bvB[j] = *(const bf16x8*)(bufc + 8192 + bob + j * 1024);
        __builtin_amdgcn_s_setprio(1);
#pragma unroll
        for (int f = 0; f < 4; ++f)
#pragma unroll
            for (int j = 0; j < 4; ++j)
                acc[4 + f][j] = __builtin_amdgcn_mfma_f32_16x16x32_bf16(
                    avB[f], bvA[j], acc[4 + f][j], 0, 0, 0);
        __builtin_amdgcn_s_setprio(0);

        // ======== X2: MFMA(ks1,mq0); read avB<-A(ks1,mq1); stage r1,r2,r6,r7
#pragma unroll
        for (int f = 0; f < 4; ++f)
            avB[f] = *(const bf16x8*)(bufc + 8192 + 4096 + aob + f * 1024);
        stage(u + 2, 1, bufc); stage(u + 2, 2, bufc);
        stage(u + 2, 6, bufc); stage(u + 2, 7, bufc);
        __builtin_amdgcn_s_setprio(1);
#pragma unroll
        for (int f = 0; f < 4; ++f)
#pragma unroll
            for (int j = 0; j < 4; ++j)
                acc[f][j] = __builtin_amdgcn_mfma_f32_16x16x32_bf16(
                    avA[f], bvB[j], acc[f][j], 0, 0, 0);
        __builtin_amdgcn_s_setprio(0);

        // ======== X3: vmcnt+beta; MFMA(ks1,mq1); pre-read next tile; stage r3
        if (u + 2 < NT) asm volatile("s_waitcnt vmcnt(7)" ::: "memory");
        else            asm volatile("s_waitcnt vmcnt(0)" ::: "memory");
        asm volatile("s_barrier" ::: "memory");          // beta: bufn ready
        if (u + 1 < NT) {
#pragma unroll
            for (int f = 0; f < 4; ++f)
                avA[f] = *(const bf16x8*)(bufn + aob + f * 1024);
#pragma unroll
            for (int j = 0; j < 4; ++j)
                bvA[j] = *(const bf16x8*)(bufn + bob + j * 1024);
        }
        stage(u + 2, 3, bufc);
        __builtin_amdgcn_s_setprio(1);
#pragma unroll
        for (int f = 0; f < 4; ++f)
#pragma unroll
            for (int j = 0; j < 4; ++j)
                acc[4 + f][j] = __builtin_amdgcn_mfma_f32_16x16x32_bf16(
                    avB[f], bvB[j], acc[4 + f][j], 0, 0, 0);
        __builtin_amdgcn_s_setprio(0);

        // segment boundary: acc = relu(acc + bias1)
        if (MIDRELU && u == nt1 - 1) {
#pragma unroll
            for (int j = 0; j < 4; ++j) {
                const float bb = bias1[n0 + wn * 64 + j * 16 + lr];
#pragma unroll
                for (int i = 0; i < 8; ++i)
#pragma unroll
                    for (int r = 0; r < 4; ++r)
                        acc[i][j][r] = fmaxf(acc[i][j][r] + bb, 0.f);
            }
        }
    }

    // ---- epilogue (C/D layout: col=lane&15, row=(lane>>4)*4+reg) ----
    const int cb = n0 + wn * 64 + lr;
    const int rb = m0 + wm * 128 + kq * 4;
#pragma unroll
    for (int j = 0; j < 4; ++j) {
        const int col = cb + j * 16;
        const float bv2 = bias2[col];
#pragma unroll
        for (int i = 0; i < 8; ++i)
#pragma unroll
            for (int r = 0; r < 4; ++r) {
                float v = acc[i][j][r] + bv2;
                if (ENDRELU) v = fmaxf(v, 0.f);
                C[(size_t)(rb + i * 16 + r) * ldc + col] = v;
            }
    }
}

// ---------------------------------------------------------------------------
// Split-K bf16 MFMA GEMM: P[z][M,N] += A[M,kbeg:kend] * Bt[N,kbeg:kend]^T
// 128x128 tile, BK=32, 256 threads; z = blockIdx.z selects K-slice of KS.
// ---------------------------------------------------------------------------
__global__ __launch_bounds__(256, 2)
void gemm_splitk(const u16* __restrict__ A, const u16* __restrict__ Bt,
                 float* __restrict__ P, int K, int KS, int N, int MN)
{
    __shared__ u16 sA[128 * 32];
    __shared__ u16 sB[128 * 32];
    const int tid = threadIdx.x;
    const int w = tid >> 6, l = tid & 63;
    const int m0 = blockIdx.y * 128, n0 = blockIdx.x * 128;
    const int wr = (w >> 1) * 64, wc = (w & 1) * 64;

    const int e0 = w * 512 + l * 8;
    const int r0 = e0 >> 5, c0 = e0 & 31;
    const int r1 = r0 + 64;

    const u16* gA0 = A + (size_t)(m0 + r0) * K + c0;
    const u16* gA1 = A + (size_t)(m0 + r1) * K + c0;
    const u16* gB0 = Bt + (size_t)(n0 + r0) * K + c0;
    const u16* gB1 = Bt + (size_t)(n0 + r1) * K + c0;
    u16* lA0 = sA + w * 512;
    u16* lA1 = sA + 2048 + w * 512;
    u16* lB0 = sB + w * 512;
    u16* lB1 = sB + 2048 + w * 512;

    f32x4 acc[4][4] = {};
    const int lr = l & 15, lk = (l >> 4) * 8;
    const int kbeg = blockIdx.z * KS, kend = kbeg + KS;

    for (int k0 = kbeg; k0 < kend; k0 += 32) {
        __syncthreads();
        GLOAD16(gA0 + k0, lA0);
        GLOAD16(gA1 + k0, lA1);
        GLOAD16(gB0 + k0, lB0);
        GLOAD16(gB1 + k0, lB1);
        __syncthreads();

        bf16x8 av[4], bv[4];
#pragma unroll
        for (int f = 0; f < 4; ++f) {
            av[f] = *(const bf16x8*)&sA[(wr + f * 16 + lr) * 32 + lk];
            bv[f] = *(const bf16x8*)&sB[(wc + f * 16 + lr) * 32 + lk];
        }
#pragma unroll
        for (int i = 0; i < 4; ++i)
#pragma unroll
            for (int j = 0; j < 4; ++j)
                acc[i][j] = __builtin_amdgcn_mfma_f32_16x16x32_bf16(
                    av[i], bv[j], acc[i][j], 0, 0, 0);
    }

    float* out = P + (size_t)blockIdx.z * MN;
    const int cb = n0 + wc + lr;
    const int rb = m0 + wr + (l >> 4) * 4;
#pragma unroll
    for (int j = 0; j < 4; ++j) {
        const int c = cb + j * 16;
#pragma unroll
        for (int i = 0; i < 4; ++i)
#pragma unroll
            for (int r = 0; r < 4; ++r)
                out[(size_t)(rb + i * 16 + r) * N + c] = acc[i][j][r];
    }
}

// reduce 4 split-K partials + bias (+relu), store f32 or bf16 with dst stride
template<int RELU, int OUTB>
__global__ void k_redux(const float* __restrict__ P, int MN,
                        const float* __restrict__ bias, void* __restrict__ dst,
                        int ldc, int logN)
{
    const int i4 = (blockIdx.x * 256 + threadIdx.x) * 4;
    float4 s = *(const float4*)(P + i4);
    const float4 v1 = *(const float4*)(P + (size_t)MN + i4);
    const float4 v2 = *(const float4*)(P + (size_t)2 * MN + i4);
    const float4 v3 = *(const float4*)(P + (size_t)3 * MN + i4);
    s.x += v1.x + v2.x + v3.x;
    s.y += v1.y + v2.y + v3.y;
    s.z += v1.z + v2.z + v3.z;
    s.w += v1.w + v2.w + v3.w;
    const int row = i4 >> logN, col = i4 & ((1 << logN) - 1);
    const float4 bb = *(const float4*)(bias + col);
    s.x += bb.x; s.y += bb.y; s.z += bb.z; s.w += bb.w;
    if (RELU) {
        s.x = fmaxf(s.x, 0.f); s.y = fmaxf(s.y, 0.f);
        s.z = fmaxf(s.z, 0.f); s.w = fmaxf(s.w, 0.f);
    }
    if (OUTB) {
        ushort4 o;
        o.x = f2b(s.x); o.y = f2b(s.y); o.z = f2b(s.z); o.w = f2b(s.w);
        *(ushort4*)((u16*)dst + (size_t)row * ldc + col) = o;
    } else {
        *(float4*)((float*)dst + (size_t)row * ldc + col) = s;
    }
}

// ---------------------------------------------------------------------------
// transpose + f32->bf16: Wt[n*K + k] = bf16(W[k*N + n]); K,N multiples of 64
// ---------------------------------------------------------------------------
__global__ void k_transpose(const float* __restrict__ W, u16* __restrict__ Wt,
                            int K, int N)
{
    __shared__ float tile[64][65];
    const int k0 = blockIdx.y * 64, n0 = blockIdx.x * 64;
    const int tr = threadIdx.x >> 6, tc = threadIdx.x & 63;
    for (int rr = tr; rr < 64; rr += 4)
        tile[rr][tc] = W[(size_t)(k0 + rr) * N + n0 + tc];
    __syncthreads();
    for (int rr = tr; rr < 64; rr += 4)
        Wt[(size_t)(n0 + rr) * K + k0 + tc] = f2b(tile[tc][rr]);
}

// f32 -> bf16 elementwise (n multiple of 4)
__global__ void k_f2b4(const float4* __restrict__ in, ushort4* __restrict__ out,
                       int n4)
{
    int i = blockIdx.x * 256 + threadIdx.x;
    const int stride = gridDim.x * 256;
    for (; i < n4; i += stride) {
        float4 v = in[i];
        ushort4 o;
        o.x = f2b(v.x); o.y = f2b(v.y); o.z = f2b(v.z); o.w = f2b(v.w);
        out[i] = o;
    }
}

// softmax(logits) @ emb_dist -> cat1 cols [INCH, INCH+768)
__global__ void k_softmax_embed(const float* __restrict__ logits,
                                const float* __restrict__ embd,
                                u16* __restrict__ cat1)
{
    const int i = blockIdx.x;
    const int t = threadIdx.x;     // 256
    __shared__ float red[256];
    __shared__ float pr[NCLS];
    float v = (t < NCLS) ? logits[i * NCLS + t] : -3.4e38f;
    red[t] = v; __syncthreads();
    for (int s = 128; s > 0; s >>= 1) {
        if (t < s) red[t] = fmaxf(red[t], red[t + s]);
        __syncthreads();
    }
    const float mx = red[0]; __syncthreads();
    float e = (t < NCLS) ? expf(v - mx) : 0.f;
    red[t] = e; __syncthreads();
    for (int s = 128; s > 0; s >>= 1) {
        if (t < s) red[t] += red[t + s];
        __syncthreads();
    }
    const float inv = 1.f / red[0];
    if (t < NCLS) pr[t] = e * inv;
    __syncthreads();
    for (int j = t; j < EMB_; j += 256) {
        float s = 0.f;
        for (int k = 0; k < NCLS; ++k) s += pr[k] * embd[k * EMB_ + j];
        cat1[(size_t)i * 4992 + INCH + j] = f2b(s);
    }
}

// pos MLP: fc1 + BN + fc2 + relu -> cat1 cols [INCH+768, INCH+768+128)
__global__ void k_pos(const float* __restrict__ pos9, const float* __restrict__ w1,
                      const float* __restrict__ b1, const float* __restrict__ g,
                      const float* __restrict__ bb, const float* __restrict__ mu,
                      const float* __restrict__ var, const float* __restrict__ w2,
                      const float* __restrict__ b2, u16* __restrict__ cat1)
{
    const int i = blockIdx.x, t = threadIdx.x;   // 128
    __shared__ float pi[9];
    __shared__ float h[32];
    if (t < 9) pi[t] = pos9[i * 9 + t];
    __syncthreads();
    if (t < 32) {
        float s = b1[t];
        for (int k = 0; k < 9; ++k) s += pi[k] * w1[k * 32 + t];
        h[t] = (s - mu[t]) * rsqrtf(var[t] + 1e-5f) * g[t] + bb[t];
    }
    __syncthreads();
    float s = b2[t];
    for (int k = 0; k < 32; ++k) s += h[k] * w2[k * GEO_ + t];
    cat1[(size_t)i * 4992 + INCH + EMB_ + t] = f2b(fmaxf(s, 0.f));
}

// pack roi -> cat1[0:4096] and aaug[768:4864]; emb_label gather -> aaug[0:768]
__global__ void k_pack(const float* __restrict__ roi, const float* __restrict__ embl,
                       const int* __restrict__ labels, u16* __restrict__ cat1,
                       u16* __restrict__ aaug)
{
    const int i = blockIdx.x, t = threadIdx.x;   // 256
    const float* r = roi + (size_t)i * INCH;
    u16* c1 = cat1 + (size_t)i * 4992;
    u16* aa = aaug + (size_t)i * 5376;
    for (int c = t; c < INCH; c += 256) {
        u16 b = f2b(r[c]);
        c1[c] = b;
        aa[EMB_ + c] = b;
    }
    const float* el = embl + (size_t)labels[i] * EMB_;
    for (int c = t; c < EMB_; c += 256) aa[c] = f2b(el[c]);
}

// geo(32) from boxes + spt1 (K=32) + relu -> bf16 [8192,512]
__global__ void k_geo_spt1(const float* __restrict__ boxes, const int* __restrict__ ridx,
                           const float* __restrict__ w1, const float* __restrict__ b1,
                           u16* __restrict__ out)
{
    const int p = blockIdx.x;        // 0..8191
    const int t = threadIdx.x;       // 256
    const int b = p >> 9;
    __shared__ float geo[32];
    if (t == 0) {
        const int i0 = ridx[p * 2 + 0];
        const int i1 = ridx[p * 2 + 1];
        const float* x = boxes + (size_t)(b * O_ + i0) * 4;
        const float* y = boxes + (size_t)(b * O_ + i1) * 4;
        float a0 = x[0], a1 = x[1], a2 = x[2], a3 = x[3];
        float c0 = y[0], c1 = y[1], c2 = y[2], c3 = y[3];
        geo[0] = a0; geo[1] = a1; geo[2] = a2; geo[3] = a3;
        geo[4] = (a0 + a2) * 0.5f; geo[5] = (a1 + a3) * 0.5f;
        geo[6] = a2 - a0; geo[7] = a3 - a1;
        geo[8] = c0; geo[9] = c1; geo[10] = c2; geo[11] = c3;
        geo[12] = (c0 + c2) * 0.5f; geo[13] = (c1 + c3) * 0.5f;
        geo[14] = c2 - c0; geo[15] = c3 - c1;
        float u0 = fminf(a0, c0), u1 = fminf(a1, c1);
        float u2 = fmaxf(a2, c2), u3 = fmaxf(a3, c3);
        geo[16] = u0; geo[17] = u1; geo[18] = u2; geo[19] = u3;
        geo[20] = (u0 + u2) * 0.5f; geo[21] = (u1 + u3) * 0.5f;
        geo[22] = u2 - u0; geo[23] = u3 - u1;
        float q0 = fmaxf(a0, c0), q1 = fmaxf(a1, c1);
        float q2 = fminf(a2, c2), q3 = fminf(a3, c3);
        if (q0 <= q2 && q1 <= q3) {
            geo[24] = q0; geo[25] = q1; geo[26] = q2; geo[27] = q3;
            geo[28] = (q0 + q2) * 0.5f; geo[29] = (q1 + q3) * 0.5f;
            geo[30] = q2 - q0; geo[31] = q3 - q1;
        } else {
            for (int k = 24; k < 32; ++k) geo[k] = 0.f;
        }
    }
    __syncthreads();
    for (int j = t; j < HID_; j += 256) {
        float s = b1[j];
#pragma unroll
        for (int k = 0; k < 32; ++k) s += geo[k] * w1[k * HID_ + j];
        out[(size_t)p * HID_ + j] = f2b(fmaxf(s, 0.f));
    }
}

// pair gather from fused (bf16) * spt (f32) -> bf16 [8192,1024]
__global__ void k_pairmul(const u16* __restrict__ fused, const float* __restrict__ spt,
                          const int* __restrict__ ridx, u16* __restrict__ apair)
{
    const int idx = blockIdx.x * 256 + threadIdx.x;   // exactly 8192*1024
    const int p = idx >> 10, c = idx & 1023;
    const int b = p >> 9;
    const int part = c >> 9;
    const int ii = ridx[p * 2 + part];
    const float fv = b2f(fused[(size_t)(b * O_ + ii) * 1024 + c]);
    apair[idx] = f2b(fv * spt[idx]);
}

// ---------------------------------------------------------------------------
extern "C" void kernel_launch(void* const* d_in, const int* in_sizes, int n_in,
                              void* d_out, int out_size, void* d_ws, size_t ws_size,
                              hipStream_t stream)
{
    (void)in_sizes; (void)n_in; (void)out_size; (void)ws_size;
    const float* roi     = (const float*)d_in[0];
    const float* unionf  = (const float*)d_in[1];
    const float* logits  = (const float*)d_in[2];
    const float* pos9    = (const float*)d_in[3];
    const float* boxes   = (const float*)d_in[4];
    const int*   labels  = (const int*)d_in[5];
    const int*   relidx  = (const int*)d_in[6];
    const float* embd    = (const float*)d_in[7];
    const float* embl    = (const float*)d_in[8];
    const float* relup_w = (const float*)d_in[9];
    const float* relup_b = (const float*)d_in[10];
    const float* updim_w = (const float*)d_in[11];
    const float* updim_b = (const float*)d_in[12];
    const float* fc1w    = (const float*)d_in[13];
    const float* fc1b    = (const float*)d_in[14];
    const float* bng     = (const float*)d_in[15];
    const float* bnb     = (const float*)d_in[16];
    const float* bnm     = (const float*)d_in[17];
    const float* bnv     = (const float*)d_in[18];
    const float* fc2w    = (const float*)d_in[19];
    const float* fc2b    = (const float*)d_in[20];
    const float* spt1w   = (const float*)d_in[21];
    const float* spt1b   = (const float*)d_in[22];
    const float* spt2w   = (const float*)d_in[23];
    const float* spt2b   = (const float*)d_in[24];
    const float* finw    = (const float*)d_in[25];
    const float* finb    = (const float*)d_in[26];
    const float* objhw   = (const float*)d_in[27];
    const float* objhb   = (const float*)d_in[28];
    const float* augw    = (const float*)d_in[29];
    const float* augb    = (const float*)d_in[30];

    char* wp = (char*)d_ws;
    auto take = [&](size_t bytes) {
        char* r = wp; wp += (bytes + 255) & ~(size_t)255; return r;
    };
    u16* wtObj   = (u16*)take((size_t)512  * 4992 * 2);
    u16* wtUpd   = (u16*)take((size_t)1024 * 5376 * 2);
    u16* wtSpt2  = (u16*)take((size_t)1024 * 512  * 2);
    u16* wtFin   = (u16*)take((size_t)2048 * 1024 * 2);
    u16* wtRelup = (u16*)take((size_t)2048 * 4096 * 2);
    u16* wtAug   = (u16*)take((size_t)2048 * 5376 * 2);
    u16* aCat1   = (u16*)take((size_t)1280 * 4992 * 2);
    u16* aAug    = (u16*)take((size_t)1280 * 5376 * 2);
    u16* aUnion  = (u16*)take((size_t)8192 * 4096 * 2);
    u16* aSpt1   = (u16*)take((size_t)8192 * 512  * 2);
    u16* fusedB  = (u16*)take((size_t)1280 * 1024 * 2);
    u16* aPair   = (u16*)take((size_t)8192 * 1024 * 2);
    float* sptF  = (float*)take((size_t)8192 * 1024 * 4);
    // split-K partial buffer: aliases (aPair + sptF) = 50.3MB >= 42MB needed;
    // dead until after the three split-K GEMMs complete.
    float* Pbuf  = (float*)aPair;

    float* outAug = (float*)d_out;                          // [1280,2048]
    float* outRel = (float*)d_out + (size_t)1280 * 2048;    // [8192,2048]

    // weights -> bf16 transposed (N x K)
    k_transpose<<<dim3(512 / 64, 4992 / 64), 256, 0, stream>>>(objhw,  wtObj,   4992, 512);
    k_transpose<<<dim3(1024 / 64, 5376 / 64), 256, 0, stream>>>(updim_w, wtUpd,  5376, 1024);
    k_transpose<<<dim3(1024 / 64, 512 / 64), 256, 0, stream>>>(spt2w,  wtSpt2,  512, 1024);
    k_transpose<<<dim3(2048 / 64, 1024 / 64), 256, 0, stream>>>(finw,   wtFin,   1024, 2048);
    k_transpose<<<dim3(2048 / 64, 4096 / 64), 256, 0, stream>>>(relup_w, wtRelup, 4096, 2048);
    k_transpose<<<dim3(2048 / 64, 5376 / 64), 256, 0, stream>>>(augw,   wtAug,   5376, 2048);

    // activations prep
    k_f2b4<<<2048, 256, 0, stream>>>((const float4*)unionf, (ushort4*)aUnion,
                                     (8192 * 4096) / 4);
    k_softmax_embed<<<1280, 256, 0, stream>>>(logits, embd, aCat1);
    k_pos<<<1280, 128, 0, stream>>>(pos9, fc1w, fc1b, bng, bnb, bnm, bnv, fc2w, fc2b, aCat1);
    k_pack<<<1280, 256, 0, stream>>>(roi, embl, labels, aCat1, aAug);

    // aug_hid = cat1 @ objhid  (split-K 4, partials f32, reduce -> bf16 cols of aAug)
    gemm_splitk<<<dim3(4, 10, 4), 256, 0, stream>>>(aCat1, wtObj, Pbuf, 4992, 1248,
                                                    512, 1280 * 512);
    k_redux<0, 1><<<640, 256, 0, stream>>>(Pbuf, 1280 * 512, objhb,
                                           (void*)(aAug + 4864), 5376, 9);
    // fused = aAug @ updim  (split-K 4 -> bf16 fusedB)
    gemm_splitk<<<dim3(8, 10, 4), 256, 0, stream>>>(aAug, wtUpd, Pbuf, 5376, 1344,
                                                    1024, 1280 * 1024);
    k_redux<0, 1><<<1280, 256, 0, stream>>>(Pbuf, 1280 * 1024, updim_b,
                                            (void*)fusedB, 1024, 10);
    // augment_out = relu(aAug @ aug_w)  (split-K 4 -> f32 outAug)
    gemm_splitk<<<dim3(16, 10, 4), 256, 0, stream>>>(aAug, wtAug, Pbuf, 5376, 1344,
                                                     2048, 1280 * 2048);
    k_redux<1, 0><<<2560, 256, 0, stream>>>(Pbuf, 1280 * 2048, augb,
                                            (void*)outAug, 2048, 11);

    // geo + spt1
    k_geo_spt1<<<8192, 256, 0, stream>>>(boxes, relidx, spt1w, spt1b, aSpt1);
    // spt = relu(spt1out @ spt2 + b) (f32), K=512 -> 8 tiles of 64
    gemm256<0, 1><<<dim3(128), 512, 0, stream>>>(
        aSpt1, 512, wtSpt2, 512, 8,
        aSpt1, 512, wtSpt2, 512, 0,
        spt2b, spt2b, sptF, 1024, 4);
    // pair_feat = gather(fused) * spt (bf16)
    k_pairmul<<<(8192 * 1024) / 256, 256, 0, stream>>>(fusedB, sptF, relidx, aPair);

    // rel_features = relu(pair@fin + finb) + union@relup + relup_b  (fused)
    // K1 = 1024 -> 16 tiles; K2 = 4096 -> 64 tiles
    gemm256<1, 0><<<dim3(256), 512, 0, stream>>>(
        aPair, 1024, wtFin, 1024, 16,
        aUnion, 4096, wtRelup, 4096, 64,
        finb, relup_b, outRel, 2048, 8);
}